// Round 7
// baseline (219.655 us; speedup 1.0000x reference)
//
#include <hip/hip_runtime.h>
#include <stdint.h>

// ---------------------------------------------------------------------------
// ProteinFeaturesNA on MI355X — R7: KSPLIT=8, register-double-buffered B
// (ulonglong2), 128-VGPR cap for 4 waves/SIMD, wave-per-row kD.
// Outputs (f32, concat): V[512][128], E[15360][128], E_idx[15360].
// ---------------------------------------------------------------------------

#define NRES   512
#define TOPK   30
#define NATOM  26
#define KTOT   10832
#define NDCP   170            // 64-k double-chunks (padded K = 10880)
#define MTOT   (NRES*TOPK)    // 15360
#define NOUT   128
#define KSPLIT 8

#define OFF_AUGX4  0u          // 512*26 float4   = 212992
#define OFF_EIDX   212992u     // 512*30 i32      =  61440 -> 274432
#define OFF_WSWZ   274432u     // 170*8*64 * 16B  = 1392640 -> 1667072
#define OFF_EPART  1667072u    // 8*15360*128 bf16 = 31457280 -> 33124352

#define OUT_V     0
#define OUT_E     (NRES*NOUT)            // 65536
#define OUT_EIDX  (OUT_E + MTOT*NOUT)    // 2031616

typedef __attribute__((ext_vector_type(4))) float f32x4;

#define SA_C   0.96089792702915984f     // sqrt(log2 e)/1.25
#define MU0_C  1.9217958540583197f      // 2*SA
#define MUS_C  1.2811972360388798f      // (4/3)*SA

__device__ __forceinline__ unsigned short f2bf(float f) {
    unsigned u = __builtin_bit_cast(unsigned, f);
    return (unsigned short)((u + 0x7fffu + ((u >> 16) & 1u)) >> 16);
}
__device__ __forceinline__ float bf2f(unsigned short u) {
    return __builtin_bit_cast(float, (unsigned)u << 16);
}
__device__ __forceinline__ unsigned long long shfl_xor_u64(unsigned long long v, int m) {
    unsigned lo = (unsigned)v, hi = (unsigned)(v >> 32);
    lo = (unsigned)__shfl_xor((int)lo, m, 64);
    hi = (unsigned)__shfl_xor((int)hi, m, 64);
    return ((unsigned long long)hi << 32) | lo;
}
__device__ __forceinline__ float fexp2(float x) { return __builtin_amdgcn_exp2f(x); }
__device__ __forceinline__ float fsqrtf(float x) { return __builtin_amdgcn_sqrtf(x); }

// 8 RBF features (window start fh*8) via center-chain: 3 exp2 + 12 mul.
__device__ __forceinline__ unsigned long long gen8c(float4 xi, float4 xj,
                                                    float mu3, float CC) {
    float s  = xi.w * xj.w;                       // 0 or 1
    float dx = xi.x - xj.x, dy = xi.y - xj.y, dz = xi.z - xj.z;
    float d2 = __builtin_fmaf(dx, dx, __builtin_fmaf(dy, dy,
               __builtin_fmaf(dz, dz, 1e-6f)));
    float Ds = fsqrtf(d2) * SA_C;
    Ds = fminf(Ds, 45.0f);                        // keeps ratio exp2 args < 128
    Ds = (s == 0.0f) ? 45.0f : Ds;                // masked -> all features 0
    float u  = Ds - mu3;                          // center = local feature 3
    float e3 = fexp2(-(u * u));
    float r  = fexp2(__builtin_fmaf( 2.0f*MUS_C, u, -(MUS_C*MUS_C)));
    float sd = fexp2(__builtin_fmaf(-2.0f*MUS_C, u, -(MUS_C*MUS_C)));
    float e4 = e3*r;  r  *= CC;
    float e5 = e4*r;  r  *= CC;
    float e6 = e5*r;  r  *= CC;
    float e7 = e6*r;
    float e2 = e3*sd; sd *= CC;
    float e1 = e2*sd; sd *= CC;
    float e0 = e1*sd;
    int r0 = __builtin_amdgcn_cvt_pk_fp8_f32(e0, e1, 0, false);
    r0     = __builtin_amdgcn_cvt_pk_fp8_f32(e2, e3, r0, true);
    int r1 = __builtin_amdgcn_cvt_pk_fp8_f32(e4, e5, 0, false);
    r1     = __builtin_amdgcn_cvt_pk_fp8_f32(e6, e7, r1, true);
    return (unsigned long long)(unsigned)r0 | ((unsigned long long)(unsigned)r1 << 32);
}

// --------------------------------------------------------------- kernel AB --
__global__ __launch_bounds__(128) void kAB(
    const float* __restrict__ X, const float* __restrict__ Xm,
    const float* __restrict__ prot, const float* __restrict__ dna,
    const float* __restrict__ rna, const int* __restrict__ ptype,
    const float* __restrict__ Wn, const float* __restrict__ gn,
    const float* __restrict__ bn, char* __restrict__ ws,
    float* __restrict__ out)
{
    const int i = blockIdx.x, t = threadIdx.x;
    float4* augX4 = (float4*)(ws + OFF_AUGX4);
    int*    Eidx  = (int*)(ws + OFF_EIDX);
    const float* Xi = X + i * 72;

    if (t < 26) {
        float x, y, z, mk;
        if (t < 24) {
            x = Xi[t*3]; y = Xi[t*3+1]; z = Xi[t*3+2];
            mk = Xm[i*24 + t];
        } else if (t == 24) {
            float b0 = Xi[3]-Xi[0], b1 = Xi[4]-Xi[1], b2 = Xi[5]-Xi[2];
            float c0 = Xi[6]-Xi[3], c1 = Xi[7]-Xi[4], c2 = Xi[8]-Xi[5];
            float a0 = b1*c2-b2*c1, a1 = b2*c0-b0*c2, a2 = b0*c1-b1*c0;
            x = -0.58273431f*a0 + 0.56802827f*b0 - 0.54067466f*c0 + Xi[3];
            y = -0.58273431f*a1 + 0.56802827f*b1 - 0.54067466f*c1 + Xi[4];
            z = -0.58273431f*a2 + 0.56802827f*b2 - 0.54067466f*c2 + Xi[5];
            mk = prot[i];
        } else {
            const float* O4 = Xi + 33; const float* C1 = Xi + 45; const float* C2 = Xi + 42;
            float b0 = C1[0]-O4[0], b1 = C1[1]-O4[1], b2 = C1[2]-O4[2];
            float c0 = C2[0]-C1[0], c1 = C2[1]-C1[1], c2 = C2[2]-C1[2];
            float a0 = b1*c2-b2*c1, a1 = b2*c0-b0*c2, a2 = b0*c1-b1*c0;
            x = -0.56967352f*a0 + 0.51055973f*b0 - 0.53122153f*c0 + C1[0];
            y = -0.56967352f*a1 + 0.51055973f*b1 - 0.53122153f*c1 + C1[1];
            z = -0.56967352f*a2 + 0.51055973f*b2 - 0.53122153f*c2 + C1[2];
            mk = dna[i] + rna[i];
        }
        augX4[i*26 + t] = make_float4(x, y, z, mk);
    }

    // V layernorm (all 128 threads)
    __shared__ float red[4];
    int ty = ptype[i];
    float v = Wn[t*3 + ty];
    float s = v;
    #pragma unroll
    for (int off = 32; off; off >>= 1) s += __shfl_xor(s, off, 64);
    if ((t & 63) == 0) red[t>>6] = s;
    __syncthreads();
    float mean = (red[0] + red[1]) * (1.0f/128.0f);
    float d = v - mean;
    float s2 = d*d;
    #pragma unroll
    for (int off = 32; off; off >>= 1) s2 += __shfl_xor(s2, off, 64);
    if ((t & 63) == 0) red[2 + (t>>6)] = s2;
    __syncthreads();
    float var = (red[2] + red[3]) * (1.0f/128.0f);
    out[OUT_V + i*NOUT + t] = d * rsqrtf(var + 1e-5f) * gn[t] + bn[t];

    // top-30 (wave 0 only); Xc[j] = Ca[j] + C1'[j] computed inline
    if (t >= 64) return;
    const int l = t;
    float xi0 = Xi[3] + Xi[45], xi1 = Xi[4] + Xi[46], xi2 = Xi[5] + Xi[47];
    unsigned long long cand[8];
    #pragma unroll
    for (int sg = 0; sg < 8; sg++) {
        int j = sg*64 + l;
        const float* Xj = X + j*72;
        float c0 = Xj[3] + Xj[45], c1 = Xj[4] + Xj[46], c2 = Xj[5] + Xj[47];
        float dx = xi0 - c0, dy = xi1 - c1, dz = xi2 - c2;
        float dd = __fadd_rn(__fadd_rn(__fadd_rn(__fmul_rn(dx,dx), __fmul_rn(dy,dy)),
                                       __fmul_rn(dz,dz)), 1e-6f);
        float D = sqrtf(dd);
        cand[sg] = ((unsigned long long)__builtin_bit_cast(unsigned, D) << 32) | (unsigned)j;
    }
    for (int m = 0; m < TOPK; m++) {
        unsigned long long k = cand[0];
        #pragma unroll
        for (int sg = 1; sg < 8; sg++) if (cand[sg] < k) k = cand[sg];
        #pragma unroll
        for (int off = 32; off; off >>= 1) {
            unsigned long long o = shfl_xor_u64(k, off);
            if (o < k) k = o;
        }
        if (l == 0) {
            int j = (int)(k & 0xffffffffu);
            Eidx[i*TOPK + m] = j;
            out[OUT_EIDX + i*TOPK + m] = (float)j;
        }
        #pragma unroll
        for (int sg = 0; sg < 8; sg++) if (cand[sg] == k) cand[sg] = ~0ull;
    }
}

// ---------------------------------------------------------------- kernel W --
// Coalesced: thread = (slot s, row n); reads 16 consecutive floats, writes
// two 8-B fragment pieces. Same fragment mapping as R6 (verified).
__global__ __launch_bounds__(256) void kW(const float* __restrict__ We,
                                          char* __restrict__ ws)
{
    int s = blockIdx.x*256 + threadIdx.x;      // grid (3, 128); s in [0,677)
    int n = blockIdx.y;
    if (s >= 677) return;
    const float* src = We + (size_t)n*KTOT + ((s < 676) ? (16 + s*16) : 0);
    float4 v0 = ((const float4*)src)[0];
    float4 v1 = ((const float4*)src)[1];
    float4 v2 = ((const float4*)src)[2];
    float4 v3 = ((const float4*)src)[3];

    int d = s >> 2, hc = s & 3, h = hc >> 1, cc = hc & 1;
    size_t base = OFF_WSWZ + ((size_t)(d*8 + (n >> 4))*64)*16 + (size_t)cc*8;
    {   // fh = 0: feats 0..7
        int r0 = __builtin_amdgcn_cvt_pk_fp8_f32(v0.x, v0.y, 0, false);
        r0     = __builtin_amdgcn_cvt_pk_fp8_f32(v0.z, v0.w, r0, true);
        int r1 = __builtin_amdgcn_cvt_pk_fp8_f32(v1.x, v1.y, 0, false);
        r1     = __builtin_amdgcn_cvt_pk_fp8_f32(v1.z, v1.w, r1, true);
        int lane = h*32 + (n & 15);
        *(uint2*)(ws + base + (size_t)lane*16) = make_uint2((unsigned)r0, (unsigned)r1);
    }
    {   // fh = 1: feats 8..15
        int r0 = __builtin_amdgcn_cvt_pk_fp8_f32(v2.x, v2.y, 0, false);
        r0     = __builtin_amdgcn_cvt_pk_fp8_f32(v2.z, v2.w, r0, true);
        int r1 = __builtin_amdgcn_cvt_pk_fp8_f32(v3.x, v3.y, 0, false);
        r1     = __builtin_amdgcn_cvt_pk_fp8_f32(v3.z, v3.w, r1, true);
        int lane = h*32 + 16 + (n & 15);
        *(uint2*)(ws + base + (size_t)lane*16) = make_uint2((unsigned)r0, (unsigned)r1);
    }
}

// ---------------------------------------------------------------- kernel C --
// grid (240, 8): block = 4 waves, 64 rows, K-eighth q. Wave w: rows
// bx*64+w*16+mlane, all 128 cols. Register-double-buffered B, no LDS.
__global__ __launch_bounds__(256, 4) void kC(const int* __restrict__ Ridx,
                                             const int* __restrict__ chain,
                                             const float* __restrict__ Wp,
                                             const float* __restrict__ bp,
                                             char* __restrict__ ws)
{
    const int bx = blockIdx.x, q = blockIdx.y;
    const int t = threadIdx.x, lane = t & 63, w = t >> 6;
    const int mlane = lane & 15, qd = lane >> 4;
    const int h = qd >> 1, fh = qd & 1;

    const float4*     augX4 = (const float4*)(ws + OFF_AUGX4);
    const int*        Eidx  = (const int*)(ws + OFF_EIDX);
    const ulonglong2* gW2   = (const ulonglong2*)(ws + OFF_WSWZ);
    unsigned short*   Ep    = (unsigned short*)(ws + OFF_EPART)
                            + (size_t)q * MTOT * NOUT;

    const int row = bx*64 + w*16 + mlane;
    const int i   = row / TOPK;
    const int j   = Eidx[row];

    int dcode;
    {
        int off  = Ridx[i] - Ridx[j];
        int same = (chain[i] == chain[j]);
        int dc = off + 32; dc = dc < 0 ? 0 : (dc > 64 ? 64 : dc);
        dcode = same ? dc : 65;
    }

    const float mu3 = MU0_C + (float)(fh*8 + 3) * MUS_C;   // window center
    const float CC  = fexp2(-2.0f * MUS_C * MUS_C);

    const float4* Ai = augX4 + i*26;
    const float4* Aj = augX4 + j*26;

    f32x4 acc[8];
    #pragma unroll
    for (int nt = 0; nt < 8; nt++) acc[nt] = (f32x4){0.f,0.f,0.f,0.f};

    // K partition over 170 dcp: d0 = {0,22,44,65,86,107,128,149},
    // RBF iters ni = {22,22,21,21,21,21,21,20}; q==7 adds tail d=169.
    const int d0 = q*21 + (q < 2 ? q : 2);
    const int ni = (q < 2) ? 22 : ((q == 7) ? 20 : 21);

    // slot state: p0 = 4*d + 2h = a*26 + rem
    int p0s = 4*d0 + 2*h;
    int a = p0s / 26, rem = p0s - a*26;
    float4 xi  = Ai[a];
    float4 xj0 = Aj[rem];
    float4 xj1 = Aj[rem + 1];

    const ulonglong2* Wb = gW2 + (size_t)d0*512 + lane;
    ulonglong2 bc[8];
    #pragma unroll
    for (int nt = 0; nt < 8; nt++) bc[nt] = Wb[nt*64];
    Wb += 512;

    for (int dd = 0; dd < ni; dd++) {
        const bool more = (dd + 1 < ni) || (q == 7);
        ulonglong2 bn[8];
        if (more) {
            #pragma unroll
            for (int nt = 0; nt < 8; nt++) bn[nt] = Wb[nt*64];
            Wb += 512;
        }

        // next-iter state + coordinate prefetch
        int remn = rem + 4;
        int an   = a + (remn >= 26 ? 1 : 0);
        remn     = (remn >= 26) ? remn - 26 : remn;
        float4 xin  = Ai[an];
        float4 xj0n = Aj[remn];
        float4 xj1n = Aj[remn + 1];

        unsigned long long a0 = gen8c(xi, xj0, mu3, CC);
        unsigned long long a1 = gen8c(xi, xj1, mu3, CC);

        #pragma unroll
        for (int nt = 0; nt < 8; nt++) {
            acc[nt] = __builtin_amdgcn_mfma_f32_16x16x32_fp8_fp8((long)a0, (long)bc[nt].x, acc[nt], 0, 0, 0);
            acc[nt] = __builtin_amdgcn_mfma_f32_16x16x32_fp8_fp8((long)a1, (long)bc[nt].y, acc[nt], 0, 0, 0);
        }

        if (more) {
            #pragma unroll
            for (int nt = 0; nt < 8; nt++) bc[nt] = bn[nt];
        }
        xi = xin; xj0 = xj0n; xj1 = xj1n; a = an; rem = remn;
    }

    if (q == 7) {   // tail d=169: slots 676,677 (h=0) / 678,679 (h=1)
        unsigned long long a0 = 0, a1 = 0;
        if (h == 0) {
            float e[8];
            #pragma unroll
            for (int ff = 0; ff < 8; ff++) {
                int fc = fh*8 + ff;
                e[ff] = Wp[fc*66 + dcode] + bp[fc];
            }
            int r0 = __builtin_amdgcn_cvt_pk_fp8_f32(e[0], e[1], 0, false);
            r0     = __builtin_amdgcn_cvt_pk_fp8_f32(e[2], e[3], r0, true);
            int r1 = __builtin_amdgcn_cvt_pk_fp8_f32(e[4], e[5], 0, false);
            r1     = __builtin_amdgcn_cvt_pk_fp8_f32(e[6], e[7], r1, true);
            a0 = (unsigned long long)(unsigned)r0 | ((unsigned long long)(unsigned)r1 << 32);
        }
        #pragma unroll
        for (int nt = 0; nt < 8; nt++) {
            acc[nt] = __builtin_amdgcn_mfma_f32_16x16x32_fp8_fp8((long)a0, (long)bc[nt].x, acc[nt], 0, 0, 0);
            acc[nt] = __builtin_amdgcn_mfma_f32_16x16x32_fp8_fp8((long)a1, (long)bc[nt].y, acc[nt], 0, 0, 0);
        }
    }

    // epilogue: bf16 partials. D layout: col = lane&15, row = qd*4 + rr.
    #pragma unroll
    for (int nt = 0; nt < 8; nt++) {
        int col = nt*16 + mlane;
        #pragma unroll
        for (int rr = 0; rr < 4; rr++) {
            int grow = bx*64 + w*16 + qd*4 + rr;
            Ep[(size_t)grow*NOUT + col] = f2bf(acc[nt][rr]);
        }
    }
}

// ---------------------------------------------------------------- kernel D --
// Wave per row: 64 lanes x 2 cols (uint bf16-pair loads), shuffle-only LN.
__global__ __launch_bounds__(256) void kD(const float* __restrict__ ge,
                                          const float* __restrict__ be,
                                          char* __restrict__ ws,
                                          float* __restrict__ out)
{
    const unsigned* Ep = (const unsigned*)(ws + OFF_EPART);
    const int t = threadIdx.x, wv = t >> 6, lane = t & 63;
    const int row = blockIdx.x*4 + wv;
    const size_t qs = (size_t)MTOT * 64;           // uints per partial set
    size_t b = (size_t)row*64 + lane;

    float v0 = 0.f, v1 = 0.f;
    #pragma unroll
    for (int qq = 0; qq < KSPLIT; qq++) {
        unsigned u = Ep[b + (size_t)qq*qs];
        v0 += bf2f((unsigned short)(u & 0xffffu));
        v1 += bf2f((unsigned short)(u >> 16));
    }

    float S = v0 + v1, Q = v0*v0 + v1*v1;
    #pragma unroll
    for (int off = 32; off; off >>= 1) {
        S += __shfl_xor(S, off, 64);
        Q += __shfl_xor(Q, off, 64);
    }
    float mean = S * (1.0f/128.0f);
    float var  = Q * (1.0f/128.0f) - mean*mean;
    float rstd = rsqrtf(var + 1e-5f);
    float2 o;
    o.x = (v0 - mean) * rstd * ge[2*lane]   + be[2*lane];
    o.y = (v1 - mean) * rstd * ge[2*lane+1] + be[2*lane+1];
    ((float2*)(out + OUT_E))[(size_t)row*64 + lane] = o;
}

// ------------------------------------------------------------------- launch --
extern "C" void kernel_launch(void* const* d_in, const int* in_sizes, int n_in,
                              void* d_out, int out_size, void* d_ws, size_t ws_size,
                              hipStream_t stream)
{
    const float* X     = (const float*)d_in[0];
    const int*   Ridx  = (const int*)d_in[2];
    const int*   chain = (const int*)d_in[3];
    const float* Xm    = (const float*)d_in[4];
    const float* prot  = (const float*)d_in[5];
    const float* dna   = (const float*)d_in[6];
    const float* rna   = (const float*)d_in[7];
    const int*   ptype = (const int*)d_in[8];
    const float* Wp    = (const float*)d_in[9];
    const float* bp    = (const float*)d_in[10];
    const float* We    = (const float*)d_in[11];
    const float* Wn    = (const float*)d_in[12];
    const float* ge    = (const float*)d_in[13];
    const float* be    = (const float*)d_in[14];
    const float* gn    = (const float*)d_in[15];
    const float* bn    = (const float*)d_in[16];
    char* ws = (char*)d_ws;
    float* out = (float*)d_out;

    kW<<<dim3(3, 128), dim3(256), 0, stream>>>(We, ws);
    kAB<<<dim3(NRES), dim3(128), 0, stream>>>(X, Xm, prot, dna, rna, ptype, Wn, gn, bn, ws, out);
    kC<<<dim3(MTOT/64, KSPLIT), dim3(256), 0, stream>>>(Ridx, chain, Wp, bp, ws);
    kD<<<dim3(MTOT/4), dim3(256), 0, stream>>>(ge, be, ws, out);
}

// Round 8
// 194.934 us; speedup vs baseline: 1.1268x; 1.1268x over previous
//
#include <hip/hip_runtime.h>
#include <stdint.h>

// ---------------------------------------------------------------------------
// ProteinFeaturesNA on MI355X — R8: 32 rows per wave (2 A-tiles per B frag,
// halves B traffic), KSPLIT=8, no reg-dbuf (R7's spill reverted), fused prep.
// Outputs (f32, concat): V[512][128], E[15360][128], E_idx[15360].
// Dispatches: kPrep (kW+kAB fused), kC, kD.
// ---------------------------------------------------------------------------

#define NRES   512
#define TOPK   30
#define NATOM  26
#define KTOT   10832
#define NDCP   170            // 64-k double-chunks (padded K = 10880)
#define MTOT   (NRES*TOPK)    // 15360
#define NOUT   128
#define KSPLIT 8

#define OFF_AUGX4  0u          // 512*26 float4   = 212992
#define OFF_EIDX   212992u     // 512*30 i32      =  61440 -> 274432
#define OFF_WSWZ   274432u     // 170*8*64 * 16B  = 1392640 -> 1667072
#define OFF_EPART  1667072u    // 8*15360*128 bf16 = 31457280 -> 33124352

#define OUT_V     0
#define OUT_E     (NRES*NOUT)            // 65536
#define OUT_EIDX  (OUT_E + MTOT*NOUT)    // 2031616

typedef __attribute__((ext_vector_type(4))) float f32x4;

#define SA_C   0.96089792702915984f     // sqrt(log2 e)/1.25
#define MU0_C  1.9217958540583197f      // 2*SA
#define MUS_C  1.2811972360388798f      // (4/3)*SA

__device__ __forceinline__ unsigned short f2bf(float f) {
    unsigned u = __builtin_bit_cast(unsigned, f);
    return (unsigned short)((u + 0x7fffu + ((u >> 16) & 1u)) >> 16);
}
__device__ __forceinline__ float bf2f(unsigned short u) {
    return __builtin_bit_cast(float, (unsigned)u << 16);
}
__device__ __forceinline__ unsigned long long shfl_xor_u64(unsigned long long v, int m) {
    unsigned lo = (unsigned)v, hi = (unsigned)(v >> 32);
    lo = (unsigned)__shfl_xor((int)lo, m, 64);
    hi = (unsigned)__shfl_xor((int)hi, m, 64);
    return ((unsigned long long)hi << 32) | lo;
}
__device__ __forceinline__ float fexp2(float x) { return __builtin_amdgcn_exp2f(x); }
__device__ __forceinline__ float fsqrtf(float x) { return __builtin_amdgcn_sqrtf(x); }

// 8 RBF features (window start fh*8) via center-chain: 3 exp2 + 12 mul.
__device__ __forceinline__ unsigned long long gen8c(float4 xi, float4 xj,
                                                    float mu3, float CC) {
    float s  = xi.w * xj.w;                       // 0 or 1
    float dx = xi.x - xj.x, dy = xi.y - xj.y, dz = xi.z - xj.z;
    float d2 = __builtin_fmaf(dx, dx, __builtin_fmaf(dy, dy,
               __builtin_fmaf(dz, dz, 1e-6f)));
    float Ds = fsqrtf(d2) * SA_C;
    Ds = fminf(Ds, 45.0f);                        // keeps ratio exp2 args < 128
    Ds = (s == 0.0f) ? 45.0f : Ds;                // masked -> all features 0
    float u  = Ds - mu3;                          // center = local feature 3
    float e3 = fexp2(-(u * u));
    float r  = fexp2(__builtin_fmaf( 2.0f*MUS_C, u, -(MUS_C*MUS_C)));
    float sd = fexp2(__builtin_fmaf(-2.0f*MUS_C, u, -(MUS_C*MUS_C)));
    float e4 = e3*r;  r  *= CC;
    float e5 = e4*r;  r  *= CC;
    float e6 = e5*r;  r  *= CC;
    float e7 = e6*r;
    float e2 = e3*sd; sd *= CC;
    float e1 = e2*sd; sd *= CC;
    float e0 = e1*sd;
    int r0 = __builtin_amdgcn_cvt_pk_fp8_f32(e0, e1, 0, false);
    r0     = __builtin_amdgcn_cvt_pk_fp8_f32(e2, e3, r0, true);
    int r1 = __builtin_amdgcn_cvt_pk_fp8_f32(e4, e5, 0, false);
    r1     = __builtin_amdgcn_cvt_pk_fp8_f32(e6, e7, r1, true);
    return (unsigned long long)(unsigned)r0 | ((unsigned long long)(unsigned)r1 << 32);
}

// -------------------------------------------------------------- kernel Prep --
// blocks [0,512): kAB (aug atoms + V-LN + top-30); blocks [512,896): kW swizzle.
__global__ __launch_bounds__(256) void kPrep(
    const float* __restrict__ X, const float* __restrict__ Xm,
    const float* __restrict__ prot, const float* __restrict__ dna,
    const float* __restrict__ rna, const int* __restrict__ ptype,
    const float* __restrict__ Wn, const float* __restrict__ gn,
    const float* __restrict__ bn, const float* __restrict__ We,
    char* __restrict__ ws, float* __restrict__ out)
{
    if (blockIdx.x >= NRES) {
        // ---- kW part: idx in [0,384), s = (idx%3)*256 + t, n = idx/3 ----
        int idx = blockIdx.x - NRES;
        int n = idx / 3;
        int s = (idx - n*3)*256 + threadIdx.x;
        if (s >= 677) return;
        const float* src = We + (size_t)n*KTOT + ((s < 676) ? (16 + s*16) : 0);
        float4 v0 = ((const float4*)src)[0];
        float4 v1 = ((const float4*)src)[1];
        float4 v2 = ((const float4*)src)[2];
        float4 v3 = ((const float4*)src)[3];
        int d = s >> 2, hc = s & 3, h = hc >> 1, cc = hc & 1;
        size_t base = OFF_WSWZ + ((size_t)(d*8 + (n >> 4))*64)*16 + (size_t)cc*8;
        {   // fh = 0: feats 0..7
            int r0 = __builtin_amdgcn_cvt_pk_fp8_f32(v0.x, v0.y, 0, false);
            r0     = __builtin_amdgcn_cvt_pk_fp8_f32(v0.z, v0.w, r0, true);
            int r1 = __builtin_amdgcn_cvt_pk_fp8_f32(v1.x, v1.y, 0, false);
            r1     = __builtin_amdgcn_cvt_pk_fp8_f32(v1.z, v1.w, r1, true);
            int lane = h*32 + (n & 15);
            *(uint2*)(ws + base + (size_t)lane*16) = make_uint2((unsigned)r0, (unsigned)r1);
        }
        {   // fh = 1: feats 8..15
            int r0 = __builtin_amdgcn_cvt_pk_fp8_f32(v2.x, v2.y, 0, false);
            r0     = __builtin_amdgcn_cvt_pk_fp8_f32(v2.z, v2.w, r0, true);
            int r1 = __builtin_amdgcn_cvt_pk_fp8_f32(v3.x, v3.y, 0, false);
            r1     = __builtin_amdgcn_cvt_pk_fp8_f32(v3.z, v3.w, r1, true);
            int lane = h*32 + 16 + (n & 15);
            *(uint2*)(ws + base + (size_t)lane*16) = make_uint2((unsigned)r0, (unsigned)r1);
        }
        return;
    }

    // ---- kAB part (threads 0..127 active) ----
    const int i = blockIdx.x, t = threadIdx.x;
    if (t >= 128) return;
    float4* augX4 = (float4*)(ws + OFF_AUGX4);
    int*    Eidx  = (int*)(ws + OFF_EIDX);
    const float* Xi = X + i * 72;

    if (t < 26) {
        float x, y, z, mk;
        if (t < 24) {
            x = Xi[t*3]; y = Xi[t*3+1]; z = Xi[t*3+2];
            mk = Xm[i*24 + t];
        } else if (t == 24) {
            float b0 = Xi[3]-Xi[0], b1 = Xi[4]-Xi[1], b2 = Xi[5]-Xi[2];
            float c0 = Xi[6]-Xi[3], c1 = Xi[7]-Xi[4], c2 = Xi[8]-Xi[5];
            float a0 = b1*c2-b2*c1, a1 = b2*c0-b0*c2, a2 = b0*c1-b1*c0;
            x = -0.58273431f*a0 + 0.56802827f*b0 - 0.54067466f*c0 + Xi[3];
            y = -0.58273431f*a1 + 0.56802827f*b1 - 0.54067466f*c1 + Xi[4];
            z = -0.58273431f*a2 + 0.56802827f*b2 - 0.54067466f*c2 + Xi[5];
            mk = prot[i];
        } else {
            const float* O4 = Xi + 33; const float* C1 = Xi + 45; const float* C2 = Xi + 42;
            float b0 = C1[0]-O4[0], b1 = C1[1]-O4[1], b2 = C1[2]-O4[2];
            float c0 = C2[0]-C1[0], c1 = C2[1]-C1[1], c2 = C2[2]-C1[2];
            float a0 = b1*c2-b2*c1, a1 = b2*c0-b0*c2, a2 = b0*c1-b1*c0;
            x = -0.56967352f*a0 + 0.51055973f*b0 - 0.53122153f*c0 + C1[0];
            y = -0.56967352f*a1 + 0.51055973f*b1 - 0.53122153f*c1 + C1[1];
            z = -0.56967352f*a2 + 0.51055973f*b2 - 0.53122153f*c2 + C1[2];
            mk = dna[i] + rna[i];
        }
        augX4[i*26 + t] = make_float4(x, y, z, mk);
    }

    // V layernorm (128 threads)
    __shared__ float red[4];
    int ty = ptype[i];
    float v = Wn[t*3 + ty];
    float s = v;
    #pragma unroll
    for (int off = 32; off; off >>= 1) s += __shfl_xor(s, off, 64);
    if ((t & 63) == 0) red[t>>6] = s;
    __syncthreads();
    float mean = (red[0] + red[1]) * (1.0f/128.0f);
    float d = v - mean;
    float s2 = d*d;
    #pragma unroll
    for (int off = 32; off; off >>= 1) s2 += __shfl_xor(s2, off, 64);
    if ((t & 63) == 0) red[2 + (t>>6)] = s2;
    __syncthreads();
    float var = (red[2] + red[3]) * (1.0f/128.0f);
    out[OUT_V + i*NOUT + t] = d * rsqrtf(var + 1e-5f) * gn[t] + bn[t];

    // top-30 (wave 0 only); Xc computed inline (bit-identical ops)
    if (t >= 64) return;
    const int l = t;
    float xi0 = Xi[3] + Xi[45], xi1 = Xi[4] + Xi[46], xi2 = Xi[5] + Xi[47];
    unsigned long long cand[8];
    #pragma unroll
    for (int sg = 0; sg < 8; sg++) {
        int j = sg*64 + l;
        const float* Xj = X + j*72;
        float c0 = Xj[3] + Xj[45], c1 = Xj[4] + Xj[46], c2 = Xj[5] + Xj[47];
        float dx = xi0 - c0, dy = xi1 - c1, dz = xi2 - c2;
        float dd = __fadd_rn(__fadd_rn(__fadd_rn(__fmul_rn(dx,dx), __fmul_rn(dy,dy)),
                                       __fmul_rn(dz,dz)), 1e-6f);
        float D = sqrtf(dd);
        cand[sg] = ((unsigned long long)__builtin_bit_cast(unsigned, D) << 32) | (unsigned)j;
    }
    for (int m = 0; m < TOPK; m++) {
        unsigned long long k = cand[0];
        #pragma unroll
        for (int sg = 1; sg < 8; sg++) if (cand[sg] < k) k = cand[sg];
        #pragma unroll
        for (int off = 32; off; off >>= 1) {
            unsigned long long o = shfl_xor_u64(k, off);
            if (o < k) k = o;
        }
        if (l == 0) {
            int j = (int)(k & 0xffffffffu);
            Eidx[i*TOPK + m] = j;
            out[OUT_EIDX + i*TOPK + m] = (float)j;
        }
        #pragma unroll
        for (int sg = 0; sg < 8; sg++) if (cand[sg] == k) cand[sg] = ~0ull;
    }
}

// ---------------------------------------------------------------- kernel C --
// grid (120, 8): block = 4 waves x 32 rows = 128 rows, K-eighth q.
// Wave w: row tiles r0 = bx*128 + w*32 + mlane and r1 = r0 + 16; each B
// fragment feeds both tiles (halves B traffic vs R6). No LDS, no barriers.
__global__ __launch_bounds__(256, 3) void kC(const int* __restrict__ Ridx,
                                             const int* __restrict__ chain,
                                             const float* __restrict__ Wp,
                                             const float* __restrict__ bp,
                                             char* __restrict__ ws)
{
    const int bx = blockIdx.x, q = blockIdx.y;
    const int t = threadIdx.x, lane = t & 63, w = t >> 6;
    const int mlane = lane & 15, qd = lane >> 4;
    const int h = qd >> 1, fh = qd & 1;

    const float4*     augX4 = (const float4*)(ws + OFF_AUGX4);
    const int*        Eidx  = (const int*)(ws + OFF_EIDX);
    const ulonglong2* gW2   = (const ulonglong2*)(ws + OFF_WSWZ);
    unsigned short*   Ep    = (unsigned short*)(ws + OFF_EPART)
                            + (size_t)q * MTOT * NOUT;

    const int r0 = bx*128 + w*32 + mlane;      // A-tile 0 row
    const int r1 = r0 + 16;                    // A-tile 1 row
    const int i0 = r0 / TOPK, j0 = Eidx[r0];
    const int i1 = r1 / TOPK, j1 = Eidx[r1];

    int dc0, dc1;
    {
        int off  = Ridx[i0] - Ridx[j0];
        int same = (chain[i0] == chain[j0]);
        int dc = off + 32; dc = dc < 0 ? 0 : (dc > 64 ? 64 : dc);
        dc0 = same ? dc : 65;
        off  = Ridx[i1] - Ridx[j1];
        same = (chain[i1] == chain[j1]);
        dc = off + 32; dc = dc < 0 ? 0 : (dc > 64 ? 64 : dc);
        dc1 = same ? dc : 65;
    }

    const float mu3 = MU0_C + (float)(fh*8 + 3) * MUS_C;   // window center
    const float CC  = fexp2(-2.0f * MUS_C * MUS_C);

    const float4* Ai0 = augX4 + i0*26;
    const float4* Aj0 = augX4 + j0*26;
    const float4* Ai1 = augX4 + i1*26;
    const float4* Aj1 = augX4 + j1*26;

    f32x4 acc0[8], acc1[8];
    #pragma unroll
    for (int nt = 0; nt < 8; nt++) {
        acc0[nt] = (f32x4){0.f,0.f,0.f,0.f};
        acc1[nt] = (f32x4){0.f,0.f,0.f,0.f};
    }

    // K partition over 170 dcp: d0 = {0,22,44,65,86,107,128,149},
    // RBF iters ni = {22,22,21,21,21,21,21,20}; q==7 adds tail d=169.
    const int d0 = q*21 + (q < 2 ? q : 2);
    const int ni = (q < 2) ? 22 : ((q == 7) ? 20 : 21);

    // slot state: p0 = 4*d + 2h = a*26 + rem
    int p0s = 4*d0 + 2*h;
    int a = p0s / 26, rem = p0s - a*26;

    const ulonglong2* Wb = gW2 + (size_t)d0*512 + lane;

    for (int dd = 0; dd < ni; dd++) {
        ulonglong2 b[8];
        #pragma unroll
        for (int nt = 0; nt < 8; nt++) b[nt] = Wb[nt*64];
        Wb += 512;

        // coordinates for this iter's slots (L1-hot: 52 float4 per (i,j))
        float4 xi0 = Ai0[a], xj00 = Aj0[rem], xj01 = Aj0[rem + 1];
        float4 xi1 = Ai1[a], xj10 = Aj1[rem], xj11 = Aj1[rem + 1];

        unsigned long long a00 = gen8c(xi0, xj00, mu3, CC);
        unsigned long long a01 = gen8c(xi0, xj01, mu3, CC);
        unsigned long long a10 = gen8c(xi1, xj10, mu3, CC);
        unsigned long long a11 = gen8c(xi1, xj11, mu3, CC);

        #pragma unroll
        for (int nt = 0; nt < 8; nt++) {
            acc0[nt] = __builtin_amdgcn_mfma_f32_16x16x32_fp8_fp8((long)a00, (long)b[nt].x, acc0[nt], 0, 0, 0);
            acc0[nt] = __builtin_amdgcn_mfma_f32_16x16x32_fp8_fp8((long)a01, (long)b[nt].y, acc0[nt], 0, 0, 0);
            acc1[nt] = __builtin_amdgcn_mfma_f32_16x16x32_fp8_fp8((long)a10, (long)b[nt].x, acc1[nt], 0, 0, 0);
            acc1[nt] = __builtin_amdgcn_mfma_f32_16x16x32_fp8_fp8((long)a11, (long)b[nt].y, acc1[nt], 0, 0, 0);
        }

        int remn = rem + 4;
        a   += (remn >= 26) ? 1 : 0;
        rem  = (remn >= 26) ? remn - 26 : remn;
    }

    if (q == 7) {   // tail d=169: slots 676,677 (h=0) / 678,679 (h=1)
        ulonglong2 b[8];
        #pragma unroll
        for (int nt = 0; nt < 8; nt++) b[nt] = Wb[nt*64];

        unsigned long long a00 = 0, a10 = 0;
        if (h == 0) {
            float e0[8], e1[8];
            #pragma unroll
            for (int ff = 0; ff < 8; ff++) {
                int fc = fh*8 + ff;
                float wv = Wp[fc*66 + dc0], bv = bp[fc];
                e0[ff] = wv + bv;
                e1[ff] = Wp[fc*66 + dc1] + bv;
            }
            int r0p = __builtin_amdgcn_cvt_pk_fp8_f32(e0[0], e0[1], 0, false);
            r0p     = __builtin_amdgcn_cvt_pk_fp8_f32(e0[2], e0[3], r0p, true);
            int r1p = __builtin_amdgcn_cvt_pk_fp8_f32(e0[4], e0[5], 0, false);
            r1p     = __builtin_amdgcn_cvt_pk_fp8_f32(e0[6], e0[7], r1p, true);
            a00 = (unsigned long long)(unsigned)r0p | ((unsigned long long)(unsigned)r1p << 32);
            r0p = __builtin_amdgcn_cvt_pk_fp8_f32(e1[0], e1[1], 0, false);
            r0p = __builtin_amdgcn_cvt_pk_fp8_f32(e1[2], e1[3], r0p, true);
            r1p = __builtin_amdgcn_cvt_pk_fp8_f32(e1[4], e1[5], 0, false);
            r1p = __builtin_amdgcn_cvt_pk_fp8_f32(e1[6], e1[7], r1p, true);
            a10 = (unsigned long long)(unsigned)r0p | ((unsigned long long)(unsigned)r1p << 32);
        }
        #pragma unroll
        for (int nt = 0; nt < 8; nt++) {
            acc0[nt] = __builtin_amdgcn_mfma_f32_16x16x32_fp8_fp8((long)a00, (long)b[nt].x, acc0[nt], 0, 0, 0);
            acc1[nt] = __builtin_amdgcn_mfma_f32_16x16x32_fp8_fp8((long)a10, (long)b[nt].x, acc1[nt], 0, 0, 0);
        }
    }

    // epilogue: bf16 partials. D layout: col = lane&15, row = qd*4 + rr.
    #pragma unroll
    for (int nt = 0; nt < 8; nt++) {
        int col = nt*16 + mlane;
        #pragma unroll
        for (int rr = 0; rr < 4; rr++) {
            int g0 = bx*128 + w*32 + qd*4 + rr;
            Ep[(size_t)g0*NOUT + col]        = f2bf(acc0[nt][rr]);
            Ep[(size_t)(g0+16)*NOUT + col]   = f2bf(acc1[nt][rr]);
        }
    }
}

// ---------------------------------------------------------------- kernel D --
// Wave per row: 64 lanes x 2 cols (uint bf16-pair loads), shuffle-only LN.
__global__ __launch_bounds__(256) void kD(const float* __restrict__ ge,
                                          const float* __restrict__ be,
                                          char* __restrict__ ws,
                                          float* __restrict__ out)
{
    const unsigned* Ep = (const unsigned*)(ws + OFF_EPART);
    const int t = threadIdx.x, wv = t >> 6, lane = t & 63;
    const int row = blockIdx.x*4 + wv;
    const size_t qs = (size_t)MTOT * 64;           // uints per partial set
    size_t b = (size_t)row*64 + lane;

    float v0 = 0.f, v1 = 0.f;
    #pragma unroll
    for (int qq = 0; qq < KSPLIT; qq++) {
        unsigned u = Ep[b + (size_t)qq*qs];
        v0 += bf2f((unsigned short)(u & 0xffffu));
        v1 += bf2f((unsigned short)(u >> 16));
    }

    float S = v0 + v1, Q = v0*v0 + v1*v1;
    #pragma unroll
    for (int off = 32; off; off >>= 1) {
        S += __shfl_xor(S, off, 64);
        Q += __shfl_xor(Q, off, 64);
    }
    float mean = S * (1.0f/128.0f);
    float var  = Q * (1.0f/128.0f) - mean*mean;
    float rstd = rsqrtf(var + 1e-5f);
    float2 o;
    o.x = (v0 - mean) * rstd * ge[2*lane]   + be[2*lane];
    o.y = (v1 - mean) * rstd * ge[2*lane+1] + be[2*lane+1];
    ((float2*)(out + OUT_E))[(size_t)row*64 + lane] = o;
}

// ------------------------------------------------------------------- launch --
extern "C" void kernel_launch(void* const* d_in, const int* in_sizes, int n_in,
                              void* d_out, int out_size, void* d_ws, size_t ws_size,
                              hipStream_t stream)
{
    const float* X     = (const float*)d_in[0];
    const int*   Ridx  = (const int*)d_in[2];
    const int*   chain = (const int*)d_in[3];
    const float* Xm    = (const float*)d_in[4];
    const float* prot  = (const float*)d_in[5];
    const float* dna   = (const float*)d_in[6];
    const float* rna   = (const float*)d_in[7];
    const int*   ptype = (const int*)d_in[8];
    const float* Wp    = (const float*)d_in[9];
    const float* bp    = (const float*)d_in[10];
    const float* We    = (const float*)d_in[11];
    const float* Wn    = (const float*)d_in[12];
    const float* ge    = (const float*)d_in[13];
    const float* be    = (const float*)d_in[14];
    const float* gn    = (const float*)d_in[15];
    const float* bn    = (const float*)d_in[16];
    char* ws = (char*)d_ws;
    float* out = (float*)d_out;

    kPrep<<<dim3(NRES + 384), dim3(256), 0, stream>>>(X, Xm, prot, dna, rna,
            ptype, Wn, gn, bn, We, ws, out);
    kC<<<dim3(MTOT/128, KSPLIT), dim3(256), 0, stream>>>(Ridx, chain, Wp, bp, ws);
    kD<<<dim3(MTOT/4), dim3(256), 0, stream>>>(ge, be, ws, out);
}

// Round 9
// 184.988 us; speedup vs baseline: 1.1874x; 1.0538x over previous
//
#include <hip/hip_runtime.h>
#include <stdint.h>

// ---------------------------------------------------------------------------
// ProteinFeaturesNA on MI355X — R9: coalesced coordinate tables (kG pre-gather
// into block-organized bf16 jTab) to fix the TA/L1-scatter bottleneck.
// KSPLIT=6 (ws 28.45 MB). No LDS/barriers in kC.
// Outputs (f32, concat): V[512][128], E[15360][128], E_idx[15360].
// Dispatches: kPrep, kG, kC, kD.
// ---------------------------------------------------------------------------

#define NRES   512
#define TOPK   30
#define NATOM  26
#define KTOT   10832
#define NDCP   170            // 64-k double-chunks (padded K = 10880)
#define MTOT   (NRES*TOPK)    // 15360
#define NOUT   128
#define KSPLIT 6

#define OFF_AUGX4  0u          // 512*26 float4        = 212992
#define OFF_EIDX   212992u     // 512*30 i32           =  61440 -> 274432
#define OFF_WSWZ   274432u     // 170*8*64 * 16B       = 1392640 -> 1667072
#define OFF_JTAB   1667072u    // 120*26*128 * 8B      = 3194880 -> 4861952
#define OFF_EPART  4861952u    // 6*15360*128 bf16     = 23592960 -> 28454912

#define OUT_V     0
#define OUT_E     (NRES*NOUT)            // 65536
#define OUT_EIDX  (OUT_E + MTOT*NOUT)    // 2031616

typedef __attribute__((ext_vector_type(4))) float f32x4;

#define SA_C   0.96089792702915984f     // sqrt(log2 e)/1.25
#define MU0_C  1.9217958540583197f      // 2*SA
#define MUS_C  1.2811972360388798f      // (4/3)*SA

__device__ __forceinline__ unsigned short f2bf(float f) {
    unsigned u = __builtin_bit_cast(unsigned, f);
    return (unsigned short)((u + 0x7fffu + ((u >> 16) & 1u)) >> 16);
}
__device__ __forceinline__ float bf2f(unsigned short u) {
    return __builtin_bit_cast(float, (unsigned)u << 16);
}
__device__ __forceinline__ float bflo(unsigned u) {
    return __builtin_bit_cast(float, u << 16);
}
__device__ __forceinline__ float bfhi(unsigned u) {
    return __builtin_bit_cast(float, u & 0xffff0000u);
}
__device__ __forceinline__ unsigned long long shfl_xor_u64(unsigned long long v, int m) {
    unsigned lo = (unsigned)v, hi = (unsigned)(v >> 32);
    lo = (unsigned)__shfl_xor((int)lo, m, 64);
    hi = (unsigned)__shfl_xor((int)hi, m, 64);
    return ((unsigned long long)hi << 32) | lo;
}
__device__ __forceinline__ float fexp2(float x) { return __builtin_amdgcn_exp2f(x); }
__device__ __forceinline__ float fsqrtf(float x) { return __builtin_amdgcn_sqrtf(x); }

// 8 RBF features via center-chain: 3 exp2 + 12 mul. j-mask folded into
// sentinel coords (-3e4); i-mask via the imask flag.
__device__ __forceinline__ unsigned long long gen8c(float4 xi, float jx, float jy,
                                                    float jz, float mu3, float CC) {
    float dx = xi.x - jx, dy = xi.y - jy, dz = xi.z - jz;
    float d2 = __builtin_fmaf(dx, dx, __builtin_fmaf(dy, dy,
               __builtin_fmaf(dz, dz, 1e-6f)));
    float Ds = fsqrtf(d2) * SA_C;
    Ds = fminf(Ds, 45.0f);                        // keeps ratio exp2 args < 128
    Ds = (xi.w == 0.0f) ? 45.0f : Ds;             // i-masked -> all features 0
    float u  = Ds - mu3;                          // center = local feature 3
    float e3 = fexp2(-(u * u));
    float r  = fexp2(__builtin_fmaf( 2.0f*MUS_C, u, -(MUS_C*MUS_C)));
    float sd = fexp2(__builtin_fmaf(-2.0f*MUS_C, u, -(MUS_C*MUS_C)));
    float e4 = e3*r;  r  *= CC;
    float e5 = e4*r;  r  *= CC;
    float e6 = e5*r;  r  *= CC;
    float e7 = e6*r;
    float e2 = e3*sd; sd *= CC;
    float e1 = e2*sd; sd *= CC;
    float e0 = e1*sd;
    int r0 = __builtin_amdgcn_cvt_pk_fp8_f32(e0, e1, 0, false);
    r0     = __builtin_amdgcn_cvt_pk_fp8_f32(e2, e3, r0, true);
    int r1 = __builtin_amdgcn_cvt_pk_fp8_f32(e4, e5, 0, false);
    r1     = __builtin_amdgcn_cvt_pk_fp8_f32(e6, e7, r1, true);
    return (unsigned long long)(unsigned)r0 | ((unsigned long long)(unsigned)r1 << 32);
}

// -------------------------------------------------------------- kernel Prep --
// blocks [0,512): aug atoms + V-LN + top-30; blocks [512,896): W swizzle.
__global__ __launch_bounds__(256) void kPrep(
    const float* __restrict__ X, const float* __restrict__ Xm,
    const float* __restrict__ prot, const float* __restrict__ dna,
    const float* __restrict__ rna, const int* __restrict__ ptype,
    const float* __restrict__ Wn, const float* __restrict__ gn,
    const float* __restrict__ bn, const float* __restrict__ We,
    char* __restrict__ ws, float* __restrict__ out)
{
    if (blockIdx.x >= NRES) {
        int idx = blockIdx.x - NRES;
        int n = idx / 3;
        int s = (idx - n*3)*256 + threadIdx.x;
        if (s >= 677) return;
        const float* src = We + (size_t)n*KTOT + ((s < 676) ? (16 + s*16) : 0);
        float4 v0 = ((const float4*)src)[0];
        float4 v1 = ((const float4*)src)[1];
        float4 v2 = ((const float4*)src)[2];
        float4 v3 = ((const float4*)src)[3];
        int d = s >> 2, hc = s & 3, h = hc >> 1, cc = hc & 1;
        size_t base = OFF_WSWZ + ((size_t)(d*8 + (n >> 4))*64)*16 + (size_t)cc*8;
        {   // fh = 0: feats 0..7
            int r0 = __builtin_amdgcn_cvt_pk_fp8_f32(v0.x, v0.y, 0, false);
            r0     = __builtin_amdgcn_cvt_pk_fp8_f32(v0.z, v0.w, r0, true);
            int r1 = __builtin_amdgcn_cvt_pk_fp8_f32(v1.x, v1.y, 0, false);
            r1     = __builtin_amdgcn_cvt_pk_fp8_f32(v1.z, v1.w, r1, true);
            int lane = h*32 + (n & 15);
            *(uint2*)(ws + base + (size_t)lane*16) = make_uint2((unsigned)r0, (unsigned)r1);
        }
        {   // fh = 1: feats 8..15
            int r0 = __builtin_amdgcn_cvt_pk_fp8_f32(v2.x, v2.y, 0, false);
            r0     = __builtin_amdgcn_cvt_pk_fp8_f32(v2.z, v2.w, r0, true);
            int r1 = __builtin_amdgcn_cvt_pk_fp8_f32(v3.x, v3.y, 0, false);
            r1     = __builtin_amdgcn_cvt_pk_fp8_f32(v3.z, v3.w, r1, true);
            int lane = h*32 + 16 + (n & 15);
            *(uint2*)(ws + base + (size_t)lane*16) = make_uint2((unsigned)r0, (unsigned)r1);
        }
        return;
    }

    const int i = blockIdx.x, t = threadIdx.x;
    if (t >= 128) return;
    float4* augX4 = (float4*)(ws + OFF_AUGX4);
    int*    Eidx  = (int*)(ws + OFF_EIDX);
    const float* Xi = X + i * 72;

    if (t < 26) {
        float x, y, z, mk;
        if (t < 24) {
            x = Xi[t*3]; y = Xi[t*3+1]; z = Xi[t*3+2];
            mk = Xm[i*24 + t];
        } else if (t == 24) {
            float b0 = Xi[3]-Xi[0], b1 = Xi[4]-Xi[1], b2 = Xi[5]-Xi[2];
            float c0 = Xi[6]-Xi[3], c1 = Xi[7]-Xi[4], c2 = Xi[8]-Xi[5];
            float a0 = b1*c2-b2*c1, a1 = b2*c0-b0*c2, a2 = b0*c1-b1*c0;
            x = -0.58273431f*a0 + 0.56802827f*b0 - 0.54067466f*c0 + Xi[3];
            y = -0.58273431f*a1 + 0.56802827f*b1 - 0.54067466f*c1 + Xi[4];
            z = -0.58273431f*a2 + 0.56802827f*b2 - 0.54067466f*c2 + Xi[5];
            mk = prot[i];
        } else {
            const float* O4 = Xi + 33; const float* C1 = Xi + 45; const float* C2 = Xi + 42;
            float b0 = C1[0]-O4[0], b1 = C1[1]-O4[1], b2 = C1[2]-O4[2];
            float c0 = C2[0]-C1[0], c1 = C2[1]-C1[1], c2 = C2[2]-C1[2];
            float a0 = b1*c2-b2*c1, a1 = b2*c0-b0*c2, a2 = b0*c1-b1*c0;
            x = -0.56967352f*a0 + 0.51055973f*b0 - 0.53122153f*c0 + C1[0];
            y = -0.56967352f*a1 + 0.51055973f*b1 - 0.53122153f*c1 + C1[1];
            z = -0.56967352f*a2 + 0.51055973f*b2 - 0.53122153f*c2 + C1[2];
            mk = dna[i] + rna[i];
        }
        augX4[i*26 + t] = make_float4(x, y, z, mk);
    }

    // V layernorm (128 threads)
    __shared__ float red[4];
    int ty = ptype[i];
    float v = Wn[t*3 + ty];
    float s = v;
    #pragma unroll
    for (int off = 32; off; off >>= 1) s += __shfl_xor(s, off, 64);
    if ((t & 63) == 0) red[t>>6] = s;
    __syncthreads();
    float mean = (red[0] + red[1]) * (1.0f/128.0f);
    float d = v - mean;
    float s2 = d*d;
    #pragma unroll
    for (int off = 32; off; off >>= 1) s2 += __shfl_xor(s2, off, 64);
    if ((t & 63) == 0) red[2 + (t>>6)] = s2;
    __syncthreads();
    float var = (red[2] + red[3]) * (1.0f/128.0f);
    out[OUT_V + i*NOUT + t] = d * rsqrtf(var + 1e-5f) * gn[t] + bn[t];

    // top-30 (wave 0 only); Xc computed inline (bit-identical ops)
    if (t >= 64) return;
    const int l = t;
    float xi0 = Xi[3] + Xi[45], xi1 = Xi[4] + Xi[46], xi2 = Xi[5] + Xi[47];
    unsigned long long cand[8];
    #pragma unroll
    for (int sg = 0; sg < 8; sg++) {
        int j = sg*64 + l;
        const float* Xj = X + j*72;
        float c0 = Xj[3] + Xj[45], c1 = Xj[4] + Xj[46], c2 = Xj[5] + Xj[47];
        float dx = xi0 - c0, dy = xi1 - c1, dz = xi2 - c2;
        float dd = __fadd_rn(__fadd_rn(__fadd_rn(__fmul_rn(dx,dx), __fmul_rn(dy,dy)),
                                       __fmul_rn(dz,dz)), 1e-6f);
        float D = sqrtf(dd);
        cand[sg] = ((unsigned long long)__builtin_bit_cast(unsigned, D) << 32) | (unsigned)j;
    }
    for (int m = 0; m < TOPK; m++) {
        unsigned long long k = cand[0];
        #pragma unroll
        for (int sg = 1; sg < 8; sg++) if (cand[sg] < k) k = cand[sg];
        #pragma unroll
        for (int off = 32; off; off >>= 1) {
            unsigned long long o = shfl_xor_u64(k, off);
            if (o < k) k = o;
        }
        if (l == 0) {
            int j = (int)(k & 0xffffffffu);
            Eidx[i*TOPK + m] = j;
            out[OUT_EIDX + i*TOPK + m] = (float)j;
        }
        #pragma unroll
        for (int sg = 0; sg < 8; sg++) if (cand[sg] == k) cand[sg] = ~0ull;
    }
}

// ---------------------------------------------------------------- kernel G --
// Pre-gather: jTab[(bx*26 + a)*128 + rl] = bf16 coords of atom a of residue
// Eidx[bx*128+rl]; masked atoms -> sentinel -3e4 (=> features exactly 0).
__global__ __launch_bounds__(256) void kG(char* __restrict__ ws)
{
    const float4* augX4 = (const float4*)(ws + OFF_AUGX4);
    const int*    Eidx  = (const int*)(ws + OFF_EIDX);
    uint2*        jTab  = (uint2*)(ws + OFF_JTAB);

    const int bx = blockIdx.x, t = threadIdx.x;
    const int rl = t & 127, half = t >> 7;
    const int j = Eidx[bx*128 + rl];
    const float4* Aj = augX4 + j*26;
    #pragma unroll
    for (int aa = 0; aa < 13; aa++) {
        int a = half*13 + aa;
        float4 p = Aj[a];
        float x = p.x, y = p.y, z = p.z;
        if (p.w == 0.0f) { x = -30000.0f; y = -30000.0f; z = -30000.0f; }
        uint2 pk;
        pk.x = (unsigned)f2bf(x) | ((unsigned)f2bf(y) << 16);
        pk.y = (unsigned)f2bf(z);
        jTab[((size_t)bx*26 + a)*128 + rl] = pk;
    }
}

// ---------------------------------------------------------------- kernel C --
// grid (120, 6): block = 4 waves x 32 rows = 128 rows, K-sixth q.
// Wave w: row tiles r0 = bx*128 + w*32 + mlane, r1 = r0+16. Coords from the
// coalesced jTab; B from global. No LDS, no barriers.
__global__ __launch_bounds__(256, 3) void kC(const int* __restrict__ Ridx,
                                             const int* __restrict__ chain,
                                             const float* __restrict__ Wp,
                                             const float* __restrict__ bp,
                                             char* __restrict__ ws)
{
    const int bx = blockIdx.x, q = blockIdx.y;
    const int t = threadIdx.x, lane = t & 63, w = t >> 6;
    const int mlane = lane & 15, qd = lane >> 4;
    const int h = qd >> 1, fh = qd & 1;

    const float4*     augX4 = (const float4*)(ws + OFF_AUGX4);
    const int*        Eidx  = (const int*)(ws + OFF_EIDX);
    const ulonglong2* gW2   = (const ulonglong2*)(ws + OFF_WSWZ);
    const uint2*      jTab  = (const uint2*)(ws + OFF_JTAB) + (size_t)bx*26*128;
    unsigned short*   Ep    = (unsigned short*)(ws + OFF_EPART)
                            + (size_t)q * MTOT * NOUT;

    const int rl0 = w*32 + mlane, rl1 = rl0 + 16;
    const int r0 = bx*128 + rl0, r1 = r0 + 16;
    const int i0 = r0 / TOPK, i1 = r1 / TOPK;

    const float mu3 = MU0_C + (float)(fh*8 + 3) * MUS_C;   // window center
    const float CC  = fexp2(-2.0f * MUS_C * MUS_C);

    const float4* Ai0 = augX4 + i0*26;
    const float4* Ai1 = augX4 + i1*26;

    f32x4 acc0[8], acc1[8];
    #pragma unroll
    for (int nt = 0; nt < 8; nt++) {
        acc0[nt] = (f32x4){0.f,0.f,0.f,0.f};
        acc1[nt] = (f32x4){0.f,0.f,0.f,0.f};
    }

    // K partition over 170 dcp: d0 = {0,29,58,86,114,142},
    // RBF iters ni = {29,29,28,28,28,27}; q==5 adds tail d=169.
    const int d0 = (q < 2) ? q*29 : (58 + (q-2)*28);
    const int ni = (q < 2) ? 29 : ((q == 5) ? 27 : 28);

    // slot state: p0 = 4*d + 2h = a*26 + rem (rem even)
    int p0s = 4*d0 + 2*h;
    int a = p0s / 26, rem = p0s - a*26;

    const ulonglong2* Wb = gW2 + (size_t)d0*512 + lane;

    for (int dd = 0; dd < ni; dd++) {
        ulonglong2 b[8];
        #pragma unroll
        for (int nt = 0; nt < 8; nt++) b[nt] = Wb[nt*64];
        Wb += 512;

        // coalesced coordinate reads
        uint2 j00 = jTab[(size_t)rem*128 + rl0];
        uint2 j01 = jTab[(size_t)(rem+1)*128 + rl0];
        uint2 j10 = jTab[(size_t)rem*128 + rl1];
        uint2 j11 = jTab[(size_t)(rem+1)*128 + rl1];
        float4 xi0 = Ai0[a], xi1 = Ai1[a];

        unsigned long long a00 = gen8c(xi0, bflo(j00.x), bfhi(j00.x), bflo(j00.y), mu3, CC);
        unsigned long long a01 = gen8c(xi0, bflo(j01.x), bfhi(j01.x), bflo(j01.y), mu3, CC);
        unsigned long long a10 = gen8c(xi1, bflo(j10.x), bfhi(j10.x), bflo(j10.y), mu3, CC);
        unsigned long long a11 = gen8c(xi1, bflo(j11.x), bfhi(j11.x), bflo(j11.y), mu3, CC);

        #pragma unroll
        for (int nt = 0; nt < 8; nt++) {
            acc0[nt] = __builtin_amdgcn_mfma_f32_16x16x32_fp8_fp8((long)a00, (long)b[nt].x, acc0[nt], 0, 0, 0);
            acc0[nt] = __builtin_amdgcn_mfma_f32_16x16x32_fp8_fp8((long)a01, (long)b[nt].y, acc0[nt], 0, 0, 0);
            acc1[nt] = __builtin_amdgcn_mfma_f32_16x16x32_fp8_fp8((long)a10, (long)b[nt].x, acc1[nt], 0, 0, 0);
            acc1[nt] = __builtin_amdgcn_mfma_f32_16x16x32_fp8_fp8((long)a11, (long)b[nt].y, acc1[nt], 0, 0, 0);
        }

        int remn = rem + 4;
        a   += (remn >= 26) ? 1 : 0;
        rem  = (remn >= 26) ? remn - 26 : remn;
    }

    if (q == 5) {   // tail d=169: slots 676,677 (h=0) / 678,679 (h=1)
        ulonglong2 b[8];
        #pragma unroll
        for (int nt = 0; nt < 8; nt++) b[nt] = Wb[nt*64];

        int dc0, dc1;
        {
            int j0 = Eidx[r0], j1 = Eidx[r1];
            int off  = Ridx[i0] - Ridx[j0];
            int same = (chain[i0] == chain[j0]);
            int dc = off + 32; dc = dc < 0 ? 0 : (dc > 64 ? 64 : dc);
            dc0 = same ? dc : 65;
            off  = Ridx[i1] - Ridx[j1];
            same = (chain[i1] == chain[j1]);
            dc = off + 32; dc = dc < 0 ? 0 : (dc > 64 ? 64 : dc);
            dc1 = same ? dc : 65;
        }

        unsigned long long a00 = 0, a10 = 0;
        if (h == 0) {
            float e0[8], e1[8];
            #pragma unroll
            for (int ff = 0; ff < 8; ff++) {
                int fc = fh*8 + ff;
                float bv = bp[fc];
                e0[ff] = Wp[fc*66 + dc0] + bv;
                e1[ff] = Wp[fc*66 + dc1] + bv;
            }
            int r0p = __builtin_amdgcn_cvt_pk_fp8_f32(e0[0], e0[1], 0, false);
            r0p     = __builtin_amdgcn_cvt_pk_fp8_f32(e0[2], e0[3], r0p, true);
            int r1p = __builtin_amdgcn_cvt_pk_fp8_f32(e0[4], e0[5], 0, false);
            r1p     = __builtin_amdgcn_cvt_pk_fp8_f32(e0[6], e0[7], r1p, true);
            a00 = (unsigned long long)(unsigned)r0p | ((unsigned long long)(unsigned)r1p << 32);
            r0p = __builtin_amdgcn_cvt_pk_fp8_f32(e1[0], e1[1], 0, false);
            r0p = __builtin_amdgcn_cvt_pk_fp8_f32(e1[2], e1[3], r0p, true);
            r1p = __builtin_amdgcn_cvt_pk_fp8_f32(e1[4], e1[5], 0, false);
            r1p = __builtin_amdgcn_cvt_pk_fp8_f32(e1[6], e1[7], r1p, true);
            a10 = (unsigned long long)(unsigned)r0p | ((unsigned long long)(unsigned)r1p << 32);
        }
        #pragma unroll
        for (int nt = 0; nt < 8; nt++) {
            acc0[nt] = __builtin_amdgcn_mfma_f32_16x16x32_fp8_fp8((long)a00, (long)b[nt].x, acc0[nt], 0, 0, 0);
            acc1[nt] = __builtin_amdgcn_mfma_f32_16x16x32_fp8_fp8((long)a10, (long)b[nt].x, acc1[nt], 0, 0, 0);
        }
    }

    // epilogue: bf16 partials. D layout: col = lane&15, row = qd*4 + rr.
    #pragma unroll
    for (int nt = 0; nt < 8; nt++) {
        int col = nt*16 + mlane;
        #pragma unroll
        for (int rr = 0; rr < 4; rr++) {
            int g0 = bx*128 + w*32 + qd*4 + rr;
            Ep[(size_t)g0*NOUT + col]        = f2bf(acc0[nt][rr]);
            Ep[(size_t)(g0+16)*NOUT + col]   = f2bf(acc1[nt][rr]);
        }
    }
}

// ---------------------------------------------------------------- kernel D --
// Wave per row: 64 lanes x 2 cols (uint bf16-pair loads), shuffle-only LN.
__global__ __launch_bounds__(256) void kD(const float* __restrict__ ge,
                                          const float* __restrict__ be,
                                          char* __restrict__ ws,
                                          float* __restrict__ out)
{
    const unsigned* Ep = (const unsigned*)(ws + OFF_EPART);
    const int t = threadIdx.x, wv = t >> 6, lane = t & 63;
    const int row = blockIdx.x*4 + wv;
    const size_t qs = (size_t)MTOT * 64;           // uints per partial set
    size_t b = (size_t)row*64 + lane;

    float v0 = 0.f, v1 = 0.f;
    #pragma unroll
    for (int qq = 0; qq < KSPLIT; qq++) {
        unsigned u = Ep[b + (size_t)qq*qs];
        v0 += bf2f((unsigned short)(u & 0xffffu));
        v1 += bf2f((unsigned short)(u >> 16));
    }

    float S = v0 + v1, Q = v0*v0 + v1*v1;
    #pragma unroll
    for (int off = 32; off; off >>= 1) {
        S += __shfl_xor(S, off, 64);
        Q += __shfl_xor(Q, off, 64);
    }
    float mean = S * (1.0f/128.0f);
    float var  = Q * (1.0f/128.0f) - mean*mean;
    float rstd = rsqrtf(var + 1e-5f);
    float2 o;
    o.x = (v0 - mean) * rstd * ge[2*lane]   + be[2*lane];
    o.y = (v1 - mean) * rstd * ge[2*lane+1] + be[2*lane+1];
    ((float2*)(out + OUT_E))[(size_t)row*64 + lane] = o;
}

// ------------------------------------------------------------------- launch --
extern "C" void kernel_launch(void* const* d_in, const int* in_sizes, int n_in,
                              void* d_out, int out_size, void* d_ws, size_t ws_size,
                              hipStream_t stream)
{
    const float* X     = (const float*)d_in[0];
    const int*   Ridx  = (const int*)d_in[2];
    const int*   chain = (const int*)d_in[3];
    const float* Xm    = (const float*)d_in[4];
    const float* prot  = (const float*)d_in[5];
    const float* dna   = (const float*)d_in[6];
    const float* rna   = (const float*)d_in[7];
    const int*   ptype = (const int*)d_in[8];
    const float* Wp    = (const float*)d_in[9];
    const float* bp    = (const float*)d_in[10];
    const float* We    = (const float*)d_in[11];
    const float* Wn    = (const float*)d_in[12];
    const float* ge    = (const float*)d_in[13];
    const float* be    = (const float*)d_in[14];
    const float* gn    = (const float*)d_in[15];
    const float* bn    = (const float*)d_in[16];
    char* ws = (char*)d_ws;
    float* out = (float*)d_out;

    kPrep<<<dim3(NRES + 384), dim3(256), 0, stream>>>(X, Xm, prot, dna, rna,
            ptype, Wn, gn, bn, We, ws, out);
    kG<<<dim3(MTOT/128), dim3(256), 0, stream>>>(ws);
    kC<<<dim3(MTOT/128, KSPLIT), dim3(256), 0, stream>>>(Ridx, chain, Wp, bp, ws);
    kD<<<dim3(MTOT/4), dim3(256), 0, stream>>>(ge, be, ws, out);
}

// Round 10
// 174.723 us; speedup vs baseline: 1.2572x; 1.0587x over previous
//
#include <hip/hip_runtime.h>
#include <stdint.h>

// ---------------------------------------------------------------------------
// ProteinFeaturesNA on MI355X — R10: kG fused into kC via LDS coord staging,
// register prefetch of next-iter coords, immediate-offset B loads. KSPLIT=6.
// Outputs (f32, concat): V[512][128], E[15360][128], E_idx[15360].
// Dispatches: kPrep, kC, kD.
// ---------------------------------------------------------------------------

#define NRES   512
#define TOPK   30
#define NATOM  26
#define KTOT   10832
#define NDCP   170            // 64-k double-chunks (padded K = 10880)
#define MTOT   (NRES*TOPK)    // 15360
#define NOUT   128
#define KSPLIT 6

#define OFF_AUGX4  0u          // 512*26 float4        = 212992
#define OFF_EIDX   212992u     // 512*30 i32           =  61440 -> 274432
#define OFF_WSWZ   274432u     // 170*8*64 * 16B       = 1392640 -> 1667072
#define OFF_EPART  1667072u    // 6*15360*128 bf16     = 23592960 -> 25260032

#define OUT_V     0
#define OUT_E     (NRES*NOUT)            // 65536
#define OUT_EIDX  (OUT_E + MTOT*NOUT)    // 2031616

typedef __attribute__((ext_vector_type(4))) float f32x4;

#define SA_C   0.96089792702915984f     // sqrt(log2 e)/1.25
#define MU0_C  1.9217958540583197f      // 2*SA
#define MUS_C  1.2811972360388798f      // (4/3)*SA

__device__ __forceinline__ unsigned short f2bf(float f) {
    unsigned u = __builtin_bit_cast(unsigned, f);
    return (unsigned short)((u + 0x7fffu + ((u >> 16) & 1u)) >> 16);
}
__device__ __forceinline__ float bf2f(unsigned short u) {
    return __builtin_bit_cast(float, (unsigned)u << 16);
}
__device__ __forceinline__ float bflo(unsigned u) {
    return __builtin_bit_cast(float, u << 16);
}
__device__ __forceinline__ float bfhi(unsigned u) {
    return __builtin_bit_cast(float, u & 0xffff0000u);
}
__device__ __forceinline__ unsigned long long shfl_xor_u64(unsigned long long v, int m) {
    unsigned lo = (unsigned)v, hi = (unsigned)(v >> 32);
    lo = (unsigned)__shfl_xor((int)lo, m, 64);
    hi = (unsigned)__shfl_xor((int)hi, m, 64);
    return ((unsigned long long)hi << 32) | lo;
}
__device__ __forceinline__ float fexp2(float x) { return __builtin_amdgcn_exp2f(x); }
__device__ __forceinline__ float fsqrtf(float x) { return __builtin_amdgcn_sqrtf(x); }

// 8 RBF features via center-chain: 3 exp2 + 12 mul. j-mask folded into
// sentinel coords (-3e4); i-mask via xi.w.
__device__ __forceinline__ unsigned long long gen8c(float4 xi, float jx, float jy,
                                                    float jz, float mu3, float CC) {
    float dx = xi.x - jx, dy = xi.y - jy, dz = xi.z - jz;
    float d2 = __builtin_fmaf(dx, dx, __builtin_fmaf(dy, dy,
               __builtin_fmaf(dz, dz, 1e-6f)));
    float Ds = fsqrtf(d2) * SA_C;
    Ds = fminf(Ds, 45.0f);                        // keeps ratio exp2 args < 128
    Ds = (xi.w == 0.0f) ? 45.0f : Ds;             // i-masked -> all features 0
    float u  = Ds - mu3;                          // center = local feature 3
    float e3 = fexp2(-(u * u));
    float r  = fexp2(__builtin_fmaf( 2.0f*MUS_C, u, -(MUS_C*MUS_C)));
    float sd = fexp2(__builtin_fmaf(-2.0f*MUS_C, u, -(MUS_C*MUS_C)));
    float e4 = e3*r;  r  *= CC;
    float e5 = e4*r;  r  *= CC;
    float e6 = e5*r;  r  *= CC;
    float e7 = e6*r;
    float e2 = e3*sd; sd *= CC;
    float e1 = e2*sd; sd *= CC;
    float e0 = e1*sd;
    int r0 = __builtin_amdgcn_cvt_pk_fp8_f32(e0, e1, 0, false);
    r0     = __builtin_amdgcn_cvt_pk_fp8_f32(e2, e3, r0, true);
    int r1 = __builtin_amdgcn_cvt_pk_fp8_f32(e4, e5, 0, false);
    r1     = __builtin_amdgcn_cvt_pk_fp8_f32(e6, e7, r1, true);
    return (unsigned long long)(unsigned)r0 | ((unsigned long long)(unsigned)r1 << 32);
}

// -------------------------------------------------------------- kernel Prep --
// blocks [0,512): aug atoms + V-LN + top-30; blocks [512,896): W swizzle.
__global__ __launch_bounds__(256) void kPrep(
    const float* __restrict__ X, const float* __restrict__ Xm,
    const float* __restrict__ prot, const float* __restrict__ dna,
    const float* __restrict__ rna, const int* __restrict__ ptype,
    const float* __restrict__ Wn, const float* __restrict__ gn,
    const float* __restrict__ bn, const float* __restrict__ We,
    char* __restrict__ ws, float* __restrict__ out)
{
    if (blockIdx.x >= NRES) {
        int idx = blockIdx.x - NRES;
        int n = idx / 3;
        int s = (idx - n*3)*256 + threadIdx.x;
        if (s >= 677) return;
        const float* src = We + (size_t)n*KTOT + ((s < 676) ? (16 + s*16) : 0);
        float4 v0 = ((const float4*)src)[0];
        float4 v1 = ((const float4*)src)[1];
        float4 v2 = ((const float4*)src)[2];
        float4 v3 = ((const float4*)src)[3];
        int d = s >> 2, hc = s & 3, h = hc >> 1, cc = hc & 1;
        size_t base = OFF_WSWZ + ((size_t)(d*8 + (n >> 4))*64)*16 + (size_t)cc*8;
        {   // fh = 0: feats 0..7
            int r0 = __builtin_amdgcn_cvt_pk_fp8_f32(v0.x, v0.y, 0, false);
            r0     = __builtin_amdgcn_cvt_pk_fp8_f32(v0.z, v0.w, r0, true);
            int r1 = __builtin_amdgcn_cvt_pk_fp8_f32(v1.x, v1.y, 0, false);
            r1     = __builtin_amdgcn_cvt_pk_fp8_f32(v1.z, v1.w, r1, true);
            int lane = h*32 + (n & 15);
            *(uint2*)(ws + base + (size_t)lane*16) = make_uint2((unsigned)r0, (unsigned)r1);
        }
        {   // fh = 1: feats 8..15
            int r0 = __builtin_amdgcn_cvt_pk_fp8_f32(v2.x, v2.y, 0, false);
            r0     = __builtin_amdgcn_cvt_pk_fp8_f32(v2.z, v2.w, r0, true);
            int r1 = __builtin_amdgcn_cvt_pk_fp8_f32(v3.x, v3.y, 0, false);
            r1     = __builtin_amdgcn_cvt_pk_fp8_f32(v3.z, v3.w, r1, true);
            int lane = h*32 + 16 + (n & 15);
            *(uint2*)(ws + base + (size_t)lane*16) = make_uint2((unsigned)r0, (unsigned)r1);
        }
        return;
    }

    const int i = blockIdx.x, t = threadIdx.x;
    if (t >= 128) return;
    float4* augX4 = (float4*)(ws + OFF_AUGX4);
    int*    Eidx  = (int*)(ws + OFF_EIDX);
    const float* Xi = X + i * 72;

    if (t < 26) {
        float x, y, z, mk;
        if (t < 24) {
            x = Xi[t*3]; y = Xi[t*3+1]; z = Xi[t*3+2];
            mk = Xm[i*24 + t];
        } else if (t == 24) {
            float b0 = Xi[3]-Xi[0], b1 = Xi[4]-Xi[1], b2 = Xi[5]-Xi[2];
            float c0 = Xi[6]-Xi[3], c1 = Xi[7]-Xi[4], c2 = Xi[8]-Xi[5];
            float a0 = b1*c2-b2*c1, a1 = b2*c0-b0*c2, a2 = b0*c1-b1*c0;
            x = -0.58273431f*a0 + 0.56802827f*b0 - 0.54067466f*c0 + Xi[3];
            y = -0.58273431f*a1 + 0.56802827f*b1 - 0.54067466f*c1 + Xi[4];
            z = -0.58273431f*a2 + 0.56802827f*b2 - 0.54067466f*c2 + Xi[5];
            mk = prot[i];
        } else {
            const float* O4 = Xi + 33; const float* C1 = Xi + 45; const float* C2 = Xi + 42;
            float b0 = C1[0]-O4[0], b1 = C1[1]-O4[1], b2 = C1[2]-O4[2];
            float c0 = C2[0]-C1[0], c1 = C2[1]-C1[1], c2 = C2[2]-C1[2];
            float a0 = b1*c2-b2*c1, a1 = b2*c0-b0*c2, a2 = b0*c1-b1*c0;
            x = -0.56967352f*a0 + 0.51055973f*b0 - 0.53122153f*c0 + C1[0];
            y = -0.56967352f*a1 + 0.51055973f*b1 - 0.53122153f*c1 + C1[1];
            z = -0.56967352f*a2 + 0.51055973f*b2 - 0.53122153f*c2 + C1[2];
            mk = dna[i] + rna[i];
        }
        augX4[i*26 + t] = make_float4(x, y, z, mk);
    }

    // V layernorm (128 threads)
    __shared__ float red[4];
    int ty = ptype[i];
    float v = Wn[t*3 + ty];
    float s = v;
    #pragma unroll
    for (int off = 32; off; off >>= 1) s += __shfl_xor(s, off, 64);
    if ((t & 63) == 0) red[t>>6] = s;
    __syncthreads();
    float mean = (red[0] + red[1]) * (1.0f/128.0f);
    float d = v - mean;
    float s2 = d*d;
    #pragma unroll
    for (int off = 32; off; off >>= 1) s2 += __shfl_xor(s2, off, 64);
    if ((t & 63) == 0) red[2 + (t>>6)] = s2;
    __syncthreads();
    float var = (red[2] + red[3]) * (1.0f/128.0f);
    out[OUT_V + i*NOUT + t] = d * rsqrtf(var + 1e-5f) * gn[t] + bn[t];

    // top-30 (wave 0 only); Xc computed inline (bit-identical ops)
    if (t >= 64) return;
    const int l = t;
    float xi0 = Xi[3] + Xi[45], xi1 = Xi[4] + Xi[46], xi2 = Xi[5] + Xi[47];
    unsigned long long cand[8];
    #pragma unroll
    for (int sg = 0; sg < 8; sg++) {
        int j = sg*64 + l;
        const float* Xj = X + j*72;
        float c0 = Xj[3] + Xj[45], c1 = Xj[4] + Xj[46], c2 = Xj[5] + Xj[47];
        float dx = xi0 - c0, dy = xi1 - c1, dz = xi2 - c2;
        float dd = __fadd_rn(__fadd_rn(__fadd_rn(__fmul_rn(dx,dx), __fmul_rn(dy,dy)),
                                       __fmul_rn(dz,dz)), 1e-6f);
        float D = sqrtf(dd);
        cand[sg] = ((unsigned long long)__builtin_bit_cast(unsigned, D) << 32) | (unsigned)j;
    }
    for (int m = 0; m < TOPK; m++) {
        unsigned long long k = cand[0];
        #pragma unroll
        for (int sg = 1; sg < 8; sg++) if (cand[sg] < k) k = cand[sg];
        #pragma unroll
        for (int off = 32; off; off >>= 1) {
            unsigned long long o = shfl_xor_u64(k, off);
            if (o < k) k = o;
        }
        if (l == 0) {
            int j = (int)(k & 0xffffffffu);
            Eidx[i*TOPK + m] = j;
            out[OUT_EIDX + i*TOPK + m] = (float)j;
        }
        #pragma unroll
        for (int sg = 0; sg < 8; sg++) if (cand[sg] == k) cand[sg] = ~0ull;
    }
}

// ---------------------------------------------------------------- kernel C --
// grid (120, 6): block = 4 waves x 32 rows = 128 rows, K-sixth q.
// Coords staged in LDS (j-table 26x128 bf16, i-table 6 residues f32);
// next-iter coords prefetched in registers; B via 2 bases + imm offsets.
__global__ __launch_bounds__(256, 3) void kC(const int* __restrict__ Ridx,
                                             const int* __restrict__ chain,
                                             const float* __restrict__ Wp,
                                             const float* __restrict__ bp,
                                             char* __restrict__ ws)
{
    const int bx = blockIdx.x, q = blockIdx.y;
    const int t = threadIdx.x, lane = t & 63, w = t >> 6;
    const int mlane = lane & 15, qd = lane >> 4;
    const int h = qd >> 1, fh = qd & 1;

    const float4* augX4 = (const float4*)(ws + OFF_AUGX4);
    const int*    Eidx  = (const int*)(ws + OFF_EIDX);
    unsigned short* Ep  = (unsigned short*)(ws + OFF_EPART)
                        + (size_t)q * MTOT * NOUT;

    __shared__ uint2  jT[NATOM * 128];    // 26624 B  (bf16 x,y | z, sentinel-masked)
    __shared__ float4 iT[160];            //  2560 B  (6 residues x 26 atoms, padded)
    __shared__ int    JrowS[128];

    // ---- stage ----
    if (t < 128) JrowS[t] = Eidx[bx*128 + t];
    __syncthreads();
    const int i_base = (bx*128) / TOPK;
    if (t < 156) {
        int il = t / 26, a = t - il*26;
        int gi = i_base + il; gi = gi > 511 ? 511 : gi;
        iT[t] = augX4[(size_t)gi*26 + a];
    }
    for (int wk = t; wk < NATOM*128; wk += 256) {
        int a = wk >> 7, rl = wk & 127;
        float4 p = augX4[(size_t)JrowS[rl]*26 + a];
        float x = p.x, y = p.y, z = p.z;
        if (p.w == 0.0f) { x = -30000.0f; y = -30000.0f; z = -30000.0f; }
        uint2 pk;
        pk.x = (unsigned)f2bf(x) | ((unsigned)f2bf(y) << 16);
        pk.y = (unsigned)f2bf(z);
        jT[a*128 + rl] = pk;
    }
    __syncthreads();

    const int rl0 = w*32 + mlane, rl1 = rl0 + 16;
    const int r0 = bx*128 + rl0, r1 = r0 + 16;
    const int i0 = r0 / TOPK, i1 = r1 / TOPK;
    const int il0 = (i0 - i_base)*26, il1 = (i1 - i_base)*26;

    const float mu3 = MU0_C + (float)(fh*8 + 3) * MUS_C;   // window center
    const float CC  = fexp2(-2.0f * MUS_C * MUS_C);

    f32x4 acc0[8], acc1[8];
    #pragma unroll
    for (int nt = 0; nt < 8; nt++) {
        acc0[nt] = (f32x4){0.f,0.f,0.f,0.f};
        acc1[nt] = (f32x4){0.f,0.f,0.f,0.f};
    }

    // K partition over 170 dcp: d0 = {0,29,58,86,114,142},
    // RBF iters ni = {29,29,28,28,28,27}; q==5 adds tail d=169.
    const int d0 = (q < 2) ? q*29 : (58 + (q-2)*28);
    const int ni = (q < 2) ? 29 : ((q == 5) ? 27 : 28);

    // slot state: p0 = 4*d + 2h = a*26 + rem (rem even)
    int p0s = 4*d0 + 2*h;
    int a = p0s / 26, rem = p0s - a*26;

    // B bases: two pointers, imm offsets 0..3072
    const char* WbA = (const char*)(ws + OFF_WSWZ) + (size_t)d0*8192 + (size_t)lane*16;
    const char* WbB = WbA + 4096;

    // preload iter-0 coords
    uint2  c00 = jT[rem*128 + rl0], c01 = jT[(rem+1)*128 + rl0];
    uint2  c10 = jT[rem*128 + rl1], c11 = jT[(rem+1)*128 + rl1];
    float4 xiA = iT[il0 + a],       xiB = iT[il1 + a];

    for (int dd = 0; dd < ni; dd++) {
        ulonglong2 b[8];
        #pragma unroll
        for (int nt = 0; nt < 4; nt++)
            b[nt] = *(const ulonglong2*)(WbA + nt*1024);
        #pragma unroll
        for (int nt = 0; nt < 4; nt++)
            b[4+nt] = *(const ulonglong2*)(WbB + nt*1024);
        WbA += 8192; WbB += 8192;

        // next-iter state + register prefetch of coords
        int remn = rem + 4;
        int an   = a + (remn >= 26 ? 1 : 0);
        remn     = (remn >= 26) ? remn - 26 : remn;
        int ac   = an > 25 ? 25 : an;      // clamp (value unused when OOB)
        uint2 n00, n01, n10, n11; float4 nxiA, nxiB;
        if (dd + 1 < ni) {
            n00 = jT[remn*128 + rl0]; n01 = jT[(remn+1)*128 + rl0];
            n10 = jT[remn*128 + rl1]; n11 = jT[(remn+1)*128 + rl1];
            nxiA = iT[il0 + ac];      nxiB = iT[il1 + ac];
        }

        unsigned long long a00 = gen8c(xiA, bflo(c00.x), bfhi(c00.x), bflo(c00.y), mu3, CC);
        unsigned long long a01 = gen8c(xiA, bflo(c01.x), bfhi(c01.x), bflo(c01.y), mu3, CC);
        unsigned long long a10 = gen8c(xiB, bflo(c10.x), bfhi(c10.x), bflo(c10.y), mu3, CC);
        unsigned long long a11 = gen8c(xiB, bflo(c11.x), bfhi(c11.x), bflo(c11.y), mu3, CC);

        #pragma unroll
        for (int nt = 0; nt < 8; nt++) {
            acc0[nt] = __builtin_amdgcn_mfma_f32_16x16x32_fp8_fp8((long)a00, (long)b[nt].x, acc0[nt], 0, 0, 0);
            acc0[nt] = __builtin_amdgcn_mfma_f32_16x16x32_fp8_fp8((long)a01, (long)b[nt].y, acc0[nt], 0, 0, 0);
            acc1[nt] = __builtin_amdgcn_mfma_f32_16x16x32_fp8_fp8((long)a10, (long)b[nt].x, acc1[nt], 0, 0, 0);
            acc1[nt] = __builtin_amdgcn_mfma_f32_16x16x32_fp8_fp8((long)a11, (long)b[nt].y, acc1[nt], 0, 0, 0);
        }

        if (dd + 1 < ni) {
            c00 = n00; c01 = n01; c10 = n10; c11 = n11;
            xiA = nxiA; xiB = nxiB;
        }
        a = an; rem = remn;
    }

    if (q == 5) {   // tail d=169: slots 676,677 (h=0) / 678,679 (h=1)
        ulonglong2 b[8];
        #pragma unroll
        for (int nt = 0; nt < 4; nt++)
            b[nt] = *(const ulonglong2*)(WbA + nt*1024);
        #pragma unroll
        for (int nt = 0; nt < 4; nt++)
            b[4+nt] = *(const ulonglong2*)(WbB + nt*1024);

        int dc0, dc1;
        {
            int j0 = JrowS[rl0], j1 = JrowS[rl1];
            int off  = Ridx[i0] - Ridx[j0];
            int same = (chain[i0] == chain[j0]);
            int dc = off + 32; dc = dc < 0 ? 0 : (dc > 64 ? 64 : dc);
            dc0 = same ? dc : 65;
            off  = Ridx[i1] - Ridx[j1];
            same = (chain[i1] == chain[j1]);
            dc = off + 32; dc = dc < 0 ? 0 : (dc > 64 ? 64 : dc);
            dc1 = same ? dc : 65;
        }

        unsigned long long a00 = 0, a10 = 0;
        if (h == 0) {
            float e0[8], e1[8];
            #pragma unroll
            for (int ff = 0; ff < 8; ff++) {
                int fc = fh*8 + ff;
                float bv = bp[fc];
                e0[ff] = Wp[fc*66 + dc0] + bv;
                e1[ff] = Wp[fc*66 + dc1] + bv;
            }
            int r0p = __builtin_amdgcn_cvt_pk_fp8_f32(e0[0], e0[1], 0, false);
            r0p     = __builtin_amdgcn_cvt_pk_fp8_f32(e0[2], e0[3], r0p, true);
            int r1p = __builtin_amdgcn_cvt_pk_fp8_f32(e0[4], e0[5], 0, false);
            r1p     = __builtin_amdgcn_cvt_pk_fp8_f32(e0[6], e0[7], r1p, true);
            a00 = (unsigned long long)(unsigned)r0p | ((unsigned long long)(unsigned)r1p << 32);
            r0p = __builtin_amdgcn_cvt_pk_fp8_f32(e1[0], e1[1], 0, false);
            r0p = __builtin_amdgcn_cvt_pk_fp8_f32(e1[2], e1[3], r0p, true);
            r1p = __builtin_amdgcn_cvt_pk_fp8_f32(e1[4], e1[5], 0, false);
            r1p = __builtin_amdgcn_cvt_pk_fp8_f32(e1[6], e1[7], r1p, true);
            a10 = (unsigned long long)(unsigned)r0p | ((unsigned long long)(unsigned)r1p << 32);
        }
        #pragma unroll
        for (int nt = 0; nt < 8; nt++) {
            acc0[nt] = __builtin_amdgcn_mfma_f32_16x16x32_fp8_fp8((long)a00, (long)b[nt].x, acc0[nt], 0, 0, 0);
            acc1[nt] = __builtin_amdgcn_mfma_f32_16x16x32_fp8_fp8((long)a10, (long)b[nt].x, acc1[nt], 0, 0, 0);
        }
    }

    // epilogue: bf16 partials. D layout: col = lane&15, row = qd*4 + rr.
    #pragma unroll
    for (int nt = 0; nt < 8; nt++) {
        int col = nt*16 + mlane;
        #pragma unroll
        for (int rr = 0; rr < 4; rr++) {
            int g0 = bx*128 + w*32 + qd*4 + rr;
            Ep[(size_t)g0*NOUT + col]        = f2bf(acc0[nt][rr]);
            Ep[(size_t)(g0+16)*NOUT + col]   = f2bf(acc1[nt][rr]);
        }
    }
}

// ---------------------------------------------------------------- kernel D --
// Wave per row: 64 lanes x 2 cols (uint bf16-pair loads), shuffle-only LN.
__global__ __launch_bounds__(256) void kD(const float* __restrict__ ge,
                                          const float* __restrict__ be,
                                          char* __restrict__ ws,
                                          float* __restrict__ out)
{
    const unsigned* Ep = (const unsigned*)(ws + OFF_EPART);
    const int t = threadIdx.x, wv = t >> 6, lane = t & 63;
    const int row = blockIdx.x*4 + wv;
    const size_t qs = (size_t)MTOT * 64;           // uints per partial set
    size_t b = (size_t)row*64 + lane;

    float v0 = 0.f, v1 = 0.f;
    #pragma unroll
    for (int qq = 0; qq < KSPLIT; qq++) {
        unsigned u = Ep[b + (size_t)qq*qs];
        v0 += bf2f((unsigned short)(u & 0xffffu));
        v1 += bf2f((unsigned short)(u >> 16));
    }

    float S = v0 + v1, Q = v0*v0 + v1*v1;
    #pragma unroll
    for (int off = 32; off; off >>= 1) {
        S += __shfl_xor(S, off, 64);
        Q += __shfl_xor(Q, off, 64);
    }
    float mean = S * (1.0f/128.0f);
    float var  = Q * (1.0f/128.0f) - mean*mean;
    float rstd = rsqrtf(var + 1e-5f);
    float2 o;
    o.x = (v0 - mean) * rstd * ge[2*lane]   + be[2*lane];
    o.y = (v1 - mean) * rstd * ge[2*lane+1] + be[2*lane+1];
    ((float2*)(out + OUT_E))[(size_t)row*64 + lane] = o;
}

// ------------------------------------------------------------------- launch --
extern "C" void kernel_launch(void* const* d_in, const int* in_sizes, int n_in,
                              void* d_out, int out_size, void* d_ws, size_t ws_size,
                              hipStream_t stream)
{
    const float* X     = (const float*)d_in[0];
    const int*   Ridx  = (const int*)d_in[2];
    const int*   chain = (const int*)d_in[3];
    const float* Xm    = (const float*)d_in[4];
    const float* prot  = (const float*)d_in[5];
    const float* dna   = (const float*)d_in[6];
    const float* rna   = (const float*)d_in[7];
    const int*   ptype = (const int*)d_in[8];
    const float* Wp    = (const float*)d_in[9];
    const float* bp    = (const float*)d_in[10];
    const float* We    = (const float*)d_in[11];
    const float* Wn    = (const float*)d_in[12];
    const float* ge    = (const float*)d_in[13];
    const float* be    = (const float*)d_in[14];
    const float* gn    = (const float*)d_in[15];
    const float* bn    = (const float*)d_in[16];
    char* ws = (char*)d_ws;
    float* out = (float*)d_out;

    kPrep<<<dim3(NRES + 384), dim3(256), 0, stream>>>(X, Xm, prot, dna, rna,
            ptype, Wn, gn, bn, We, ws, out);
    kC<<<dim3(MTOT/128, KSPLIT), dim3(256), 0, stream>>>(Ridx, chain, Wp, bp, ws);
    kD<<<dim3(MTOT/4), dim3(256), 0, stream>>>(ge, be, ws, out);
}

// Round 11
// 165.904 us; speedup vs baseline: 1.3240x; 1.0532x over previous
//
#include <hip/hip_runtime.h>
#include <stdint.h>

// ---------------------------------------------------------------------------
// ProteinFeaturesNA on MI355X — R11: MX-scaled fp8 MFMA 16x16x128 (unity
// scales), lane = 2 full slots (dedup distances), 2-wave/64-row blocks,
// grid (240,6). Outputs (f32): V[512][128], E[15360][128], E_idx[15360].
// Dispatches: kPrep, kC, kD.
// ---------------------------------------------------------------------------

#define NRES   512
#define TOPK   30
#define NATOM  26
#define KTOT   10832
#define NBLK128 85            // 128-k blocks (padded K = 10880)
#define MTOT   (NRES*TOPK)    // 15360
#define NOUT   128
#define KSPLIT 6

#define OFF_AUGX4  0u          // 512*26 float4        = 212992
#define OFF_EIDX   212992u     // 512*30 i32           =  61440 -> 274432
#define OFF_WSWZ   274432u     // 85*8 frag * 2048 B   = 1392640 -> 1667072
#define OFF_EPART  1667072u    // 6*15360*128 bf16     = 23592960 -> 25260032

#define OUT_V     0
#define OUT_E     (NRES*NOUT)            // 65536
#define OUT_EIDX  (OUT_E + MTOT*NOUT)    // 2031616

typedef __attribute__((ext_vector_type(4))) float f32x4;
typedef __attribute__((ext_vector_type(8))) int   i32x8;

#define SA_C    0.96089792702915984f     // sqrt(log2 e)/1.25
#define MU0_C   1.9217958540583197f      // 2*SA
#define MUS_C   1.2811972360388798f      // (4/3)*SA
#define MUS2_C  (MUS_C*MUS_C)
#define MU3_C   (MU0_C + 3.0f*MUS_C)
#define MU11_C  (MU0_C + 11.0f*MUS_C)
#define SCL1    0x7f7f7f7f               // e8m0 unity scales (any opsel byte)

__device__ __forceinline__ unsigned short f2bf(float f) {
    unsigned u = __builtin_bit_cast(unsigned, f);
    return (unsigned short)((u + 0x7fffu + ((u >> 16) & 1u)) >> 16);
}
__device__ __forceinline__ float bf2f(unsigned short u) {
    return __builtin_bit_cast(float, (unsigned)u << 16);
}
__device__ __forceinline__ float bflo(unsigned u) {
    return __builtin_bit_cast(float, u << 16);
}
__device__ __forceinline__ float bfhi(unsigned u) {
    return __builtin_bit_cast(float, u & 0xffff0000u);
}
__device__ __forceinline__ unsigned long long shfl_xor_u64(unsigned long long v, int m) {
    unsigned lo = (unsigned)v, hi = (unsigned)(v >> 32);
    lo = (unsigned)__shfl_xor((int)lo, m, 64);
    hi = (unsigned)__shfl_xor((int)hi, m, 64);
    return ((unsigned long long)hi << 32) | lo;
}
__device__ __forceinline__ float fexp2(float x) { return __builtin_amdgcn_exp2f(x); }
__device__ __forceinline__ float fsqrtf(float x) { return __builtin_amdgcn_sqrtf(x); }

// 16 RBF features of one slot: one distance, two 8-feature center-chains.
__device__ __forceinline__ uint4 gen16(float4 xi, float jx, float jy, float jz,
                                       float CC) {
    float dx = xi.x - jx, dy = xi.y - jy, dz = xi.z - jz;
    float d2 = __builtin_fmaf(dx, dx, __builtin_fmaf(dy, dy,
               __builtin_fmaf(dz, dz, 1e-6f)));
    float Ds = fsqrtf(d2) * SA_C;
    Ds = fminf(Ds, 45.0f);
    Ds = (xi.w == 0.0f) ? 45.0f : Ds;             // i-masked -> all features 0
    uint4 o;
    {   // feats 0..7, center f3
        float u = Ds - MU3_C;
        float e3 = fexp2(-(u * u));
        float r  = fexp2(__builtin_fmaf( 2.0f*MUS_C, u, -MUS2_C));
        float sd = fexp2(__builtin_fmaf(-2.0f*MUS_C, u, -MUS2_C));
        float e4=e3*r;  r*=CC;  float e5=e4*r;  r*=CC;  float e6=e5*r;  r*=CC;  float e7=e6*r;
        float e2=e3*sd; sd*=CC; float e1=e2*sd; sd*=CC; float e0=e1*sd;
        int p = __builtin_amdgcn_cvt_pk_fp8_f32(e0, e1, 0, false);
        p     = __builtin_amdgcn_cvt_pk_fp8_f32(e2, e3, p, true);
        int q = __builtin_amdgcn_cvt_pk_fp8_f32(e4, e5, 0, false);
        q     = __builtin_amdgcn_cvt_pk_fp8_f32(e6, e7, q, true);
        o.x = (unsigned)p; o.y = (unsigned)q;
    }
    {   // feats 8..15, center f11
        float u = Ds - MU11_C;
        float e3 = fexp2(-(u * u));
        float r  = fexp2(__builtin_fmaf( 2.0f*MUS_C, u, -MUS2_C));
        float sd = fexp2(__builtin_fmaf(-2.0f*MUS_C, u, -MUS2_C));
        float e4=e3*r;  r*=CC;  float e5=e4*r;  r*=CC;  float e6=e5*r;  r*=CC;  float e7=e6*r;
        float e2=e3*sd; sd*=CC; float e1=e2*sd; sd*=CC; float e0=e1*sd;
        int p = __builtin_amdgcn_cvt_pk_fp8_f32(e0, e1, 0, false);
        p     = __builtin_amdgcn_cvt_pk_fp8_f32(e2, e3, p, true);
        int q = __builtin_amdgcn_cvt_pk_fp8_f32(e4, e5, 0, false);
        q     = __builtin_amdgcn_cvt_pk_fp8_f32(e6, e7, q, true);
        o.z = (unsigned)p; o.w = (unsigned)q;
    }
    return o;
}

// -------------------------------------------------------------- kernel Prep --
// blocks [0,512): aug atoms + V-LN + top-30; blocks [512,896): W swizzle.
// W fragment (K=128 layout): frag (d, nt) = 64 lanes x 32 B; lane
// (qd*16 + (n&15)) bytes cc*16+f = fp8 W[n][slot 8d+2qd+cc, feature f].
__global__ __launch_bounds__(256) void kPrep(
    const float* __restrict__ X, const float* __restrict__ Xm,
    const float* __restrict__ prot, const float* __restrict__ dna,
    const float* __restrict__ rna, const int* __restrict__ ptype,
    const float* __restrict__ Wn, const float* __restrict__ gn,
    const float* __restrict__ bn, const float* __restrict__ We,
    char* __restrict__ ws, float* __restrict__ out)
{
    if (blockIdx.x >= NRES) {
        int idx = blockIdx.x - NRES;
        int n = idx / 3;
        int s = (idx - n*3)*256 + threadIdx.x;
        if (s >= 677) return;
        const float* src = We + (size_t)n*KTOT + ((s < 676) ? (16 + s*16) : 0);
        float4 v0 = ((const float4*)src)[0];
        float4 v1 = ((const float4*)src)[1];
        float4 v2 = ((const float4*)src)[2];
        float4 v3 = ((const float4*)src)[3];
        int d = s >> 3, sl = s & 7, qd2 = sl >> 1, cc = sl & 1;
        size_t base = OFF_WSWZ
                    + (((size_t)(d*8 + (n >> 4))*64) + (size_t)(qd2*16 + (n & 15)))*32
                    + (size_t)cc*16;
        int r0 = __builtin_amdgcn_cvt_pk_fp8_f32(v0.x, v0.y, 0, false);
        r0     = __builtin_amdgcn_cvt_pk_fp8_f32(v0.z, v0.w, r0, true);
        int r1 = __builtin_amdgcn_cvt_pk_fp8_f32(v1.x, v1.y, 0, false);
        r1     = __builtin_amdgcn_cvt_pk_fp8_f32(v1.z, v1.w, r1, true);
        int r2 = __builtin_amdgcn_cvt_pk_fp8_f32(v2.x, v2.y, 0, false);
        r2     = __builtin_amdgcn_cvt_pk_fp8_f32(v2.z, v2.w, r2, true);
        int r3 = __builtin_amdgcn_cvt_pk_fp8_f32(v3.x, v3.y, 0, false);
        r3     = __builtin_amdgcn_cvt_pk_fp8_f32(v3.z, v3.w, r3, true);
        *(uint4*)(ws + base) = make_uint4((unsigned)r0, (unsigned)r1,
                                          (unsigned)r2, (unsigned)r3);
        return;
    }

    const int i = blockIdx.x, t = threadIdx.x;
    if (t >= 128) return;
    float4* augX4 = (float4*)(ws + OFF_AUGX4);
    int*    Eidx  = (int*)(ws + OFF_EIDX);
    const float* Xi = X + i * 72;

    if (t < 26) {
        float x, y, z, mk;
        if (t < 24) {
            x = Xi[t*3]; y = Xi[t*3+1]; z = Xi[t*3+2];
            mk = Xm[i*24 + t];
        } else if (t == 24) {
            float b0 = Xi[3]-Xi[0], b1 = Xi[4]-Xi[1], b2 = Xi[5]-Xi[2];
            float c0 = Xi[6]-Xi[3], c1 = Xi[7]-Xi[4], c2 = Xi[8]-Xi[5];
            float a0 = b1*c2-b2*c1, a1 = b2*c0-b0*c2, a2 = b0*c1-b1*c0;
            x = -0.58273431f*a0 + 0.56802827f*b0 - 0.54067466f*c0 + Xi[3];
            y = -0.58273431f*a1 + 0.56802827f*b1 - 0.54067466f*c1 + Xi[4];
            z = -0.58273431f*a2 + 0.56802827f*b2 - 0.54067466f*c2 + Xi[5];
            mk = prot[i];
        } else {
            const float* O4 = Xi + 33; const float* C1 = Xi + 45; const float* C2 = Xi + 42;
            float b0 = C1[0]-O4[0], b1 = C1[1]-O4[1], b2 = C1[2]-O4[2];
            float c0 = C2[0]-C1[0], c1 = C2[1]-C1[1], c2 = C2[2]-C1[2];
            float a0 = b1*c2-b2*c1, a1 = b2*c0-b0*c2, a2 = b0*c1-b1*c0;
            x = -0.56967352f*a0 + 0.51055973f*b0 - 0.53122153f*c0 + C1[0];
            y = -0.56967352f*a1 + 0.51055973f*b1 - 0.53122153f*c1 + C1[1];
            z = -0.56967352f*a2 + 0.51055973f*b2 - 0.53122153f*c2 + C1[2];
            mk = dna[i] + rna[i];
        }
        augX4[i*26 + t] = make_float4(x, y, z, mk);
    }

    // V layernorm (128 threads)
    __shared__ float red[4];
    int ty = ptype[i];
    float v = Wn[t*3 + ty];
    float s = v;
    #pragma unroll
    for (int off = 32; off; off >>= 1) s += __shfl_xor(s, off, 64);
    if ((t & 63) == 0) red[t>>6] = s;
    __syncthreads();
    float mean = (red[0] + red[1]) * (1.0f/128.0f);
    float d = v - mean;
    float s2 = d*d;
    #pragma unroll
    for (int off = 32; off; off >>= 1) s2 += __shfl_xor(s2, off, 64);
    if ((t & 63) == 0) red[2 + (t>>6)] = s2;
    __syncthreads();
    float var = (red[2] + red[3]) * (1.0f/128.0f);
    out[OUT_V + i*NOUT + t] = d * rsqrtf(var + 1e-5f) * gn[t] + bn[t];

    // top-30 (wave 0 only); Xc computed inline (bit-identical ops)
    if (t >= 64) return;
    const int l = t;
    float xi0 = Xi[3] + Xi[45], xi1 = Xi[4] + Xi[46], xi2 = Xi[5] + Xi[47];
    unsigned long long cand[8];
    #pragma unroll
    for (int sg = 0; sg < 8; sg++) {
        int j = sg*64 + l;
        const float* Xj = X + j*72;
        float c0 = Xj[3] + Xj[45], c1 = Xj[4] + Xj[46], c2 = Xj[5] + Xj[47];
        float dx = xi0 - c0, dy = xi1 - c1, dz = xi2 - c2;
        float dd = __fadd_rn(__fadd_rn(__fadd_rn(__fmul_rn(dx,dx), __fmul_rn(dy,dy)),
                                       __fmul_rn(dz,dz)), 1e-6f);
        float D = sqrtf(dd);
        cand[sg] = ((unsigned long long)__builtin_bit_cast(unsigned, D) << 32) | (unsigned)j;
    }
    for (int m = 0; m < TOPK; m++) {
        unsigned long long k = cand[0];
        #pragma unroll
        for (int sg = 1; sg < 8; sg++) if (cand[sg] < k) k = cand[sg];
        #pragma unroll
        for (int off = 32; off; off >>= 1) {
            unsigned long long o = shfl_xor_u64(k, off);
            if (o < k) k = o;
        }
        if (l == 0) {
            int j = (int)(k & 0xffffffffu);
            Eidx[i*TOPK + m] = j;
            out[OUT_EIDX + i*TOPK + m] = (float)j;
        }
        #pragma unroll
        for (int sg = 0; sg < 8; sg++) if (cand[sg] == k) cand[sg] = ~0ull;
    }
}

// ---------------------------------------------------------------- kernel C --
// grid (240, 6): block = 2 waves x 64 rows, K-sixth q. Wave w: row tiles
// r0 = bx*64 + w*32 + mlane, r1 = r0+16, all 128 cols. Lane (mlane, qd)
// covers k = qd*32..+31 = slots 8d+2qd, +1 per 128-k block d.
__global__ __launch_bounds__(128, 3) void kC(const int* __restrict__ Ridx,
                                             const int* __restrict__ chain,
                                             const float* __restrict__ Wp,
                                             const float* __restrict__ bp,
                                             char* __restrict__ ws)
{
    const int bx = blockIdx.x, q = blockIdx.y;
    const int t = threadIdx.x, lane = t & 63, w = t >> 6;
    const int mlane = lane & 15, qd = lane >> 4;

    const float4* augX4 = (const float4*)(ws + OFF_AUGX4);
    const int*    Eidx  = (const int*)(ws + OFF_EIDX);
    unsigned short* Ep  = (unsigned short*)(ws + OFF_EPART)
                        + (size_t)q * MTOT * NOUT;

    __shared__ uint2  jT[NATOM * 65];     // 13520 B, stride-65 padded
    __shared__ float4 iT[5 * 26];         //  2080 B
    __shared__ int    JrowS[64];

    if (t < 64) JrowS[t] = Eidx[bx*64 + t];
    __syncthreads();
    const int i_base = (bx*64) / TOPK;
    if (t < 5*26) {
        int il = t / 26, aa = t - il*26;
        int gi = i_base + il; gi = gi > 511 ? 511 : gi;
        iT[t] = augX4[(size_t)gi*26 + aa];
    }
    for (int wk = t; wk < NATOM*64; wk += 128) {
        int aa = wk >> 6, rl = wk & 63;
        float4 p = augX4[(size_t)JrowS[rl]*26 + aa];
        float x = p.x, y = p.y, z = p.z;
        if (p.w == 0.0f) { x = -30000.0f; y = -30000.0f; z = -30000.0f; }
        uint2 pk;
        pk.x = (unsigned)f2bf(x) | ((unsigned)f2bf(y) << 16);
        pk.y = (unsigned)f2bf(z);
        jT[aa*65 + rl] = pk;
    }
    __syncthreads();

    const int rl0 = w*32 + mlane, rl1 = rl0 + 16;
    const int r0 = bx*64 + rl0, r1 = r0 + 16;
    const int i0 = r0 / TOPK, i1 = r1 / TOPK;
    const int il0 = (i0 - i_base)*26, il1 = (i1 - i_base)*26;

    const float CC = fexp2(-2.0f * MUS2_C);

    f32x4 acc0[8], acc1[8];
    #pragma unroll
    for (int nt = 0; nt < 8; nt++) {
        acc0[nt] = (f32x4){0.f,0.f,0.f,0.f};
        acc1[nt] = (f32x4){0.f,0.f,0.f,0.f};
    }

    // K partition over 85 blocks: d0 = {0,15,29,43,57,71}, ni = {15,14,14,14,14,14}
    const int d0 = (q == 0) ? 0 : (1 + q*14);
    const int nmain = (q == 0) ? 15 : ((q == 5) ? 13 : 14);

    // slot state: s = d*8 + 2*qd = a*26 + rem
    int s0i = d0*8 + 2*qd;
    int a = s0i / 26, rem = s0i - a*26;

    const char* Wb = (const char*)(ws + OFF_WSWZ) + (size_t)d0*16384 + (size_t)lane*32;

    for (int dd = 0; dd < nmain; dd++) {
        i32x8 b0 = *(const i32x8*)(Wb);
        i32x8 b1 = *(const i32x8*)(Wb + 2048);
        i32x8 b2 = *(const i32x8*)(Wb + 4096);
        i32x8 b3 = *(const i32x8*)(Wb + 6144);

        int rem1 = rem + 1, a1 = a;
        if (rem1 == 26) { rem1 = 0; a1 = a + 1; }

        uint2 jR0a = jT[rem*65  + rl0], jR0b = jT[rem1*65 + rl0];
        uint2 jR1a = jT[rem*65  + rl1], jR1b = jT[rem1*65 + rl1];
        float4 xiR0a = iT[il0 + a], xiR0b = iT[il0 + a1];
        float4 xiR1a = iT[il1 + a], xiR1b = iT[il1 + a1];

        uint4 p0a = gen16(xiR0a, bflo(jR0a.x), bfhi(jR0a.x), bflo(jR0a.y), CC);
        uint4 p0b = gen16(xiR0b, bflo(jR0b.x), bfhi(jR0b.x), bflo(jR0b.y), CC);
        uint4 p1a = gen16(xiR1a, bflo(jR1a.x), bfhi(jR1a.x), bflo(jR1a.y), CC);
        uint4 p1b = gen16(xiR1b, bflo(jR1b.x), bfhi(jR1b.x), bflo(jR1b.y), CC);

        i32x8 A0, A1;
        A0[0]=p0a.x; A0[1]=p0a.y; A0[2]=p0a.z; A0[3]=p0a.w;
        A0[4]=p0b.x; A0[5]=p0b.y; A0[6]=p0b.z; A0[7]=p0b.w;
        A1[0]=p1a.x; A1[1]=p1a.y; A1[2]=p1a.z; A1[3]=p1a.w;
        A1[4]=p1b.x; A1[5]=p1b.y; A1[6]=p1b.z; A1[7]=p1b.w;

        acc0[0] = __builtin_amdgcn_mfma_scale_f32_16x16x128_f8f6f4(A0, b0, acc0[0], 0, 0, 0, SCL1, 0, SCL1);
        acc1[0] = __builtin_amdgcn_mfma_scale_f32_16x16x128_f8f6f4(A1, b0, acc1[0], 0, 0, 0, SCL1, 0, SCL1);
        acc0[1] = __builtin_amdgcn_mfma_scale_f32_16x16x128_f8f6f4(A0, b1, acc0[1], 0, 0, 0, SCL1, 0, SCL1);
        acc1[1] = __builtin_amdgcn_mfma_scale_f32_16x16x128_f8f6f4(A1, b1, acc1[1], 0, 0, 0, SCL1, 0, SCL1);
        acc0[2] = __builtin_amdgcn_mfma_scale_f32_16x16x128_f8f6f4(A0, b2, acc0[2], 0, 0, 0, SCL1, 0, SCL1);
        acc1[2] = __builtin_amdgcn_mfma_scale_f32_16x16x128_f8f6f4(A1, b2, acc1[2], 0, 0, 0, SCL1, 0, SCL1);
        acc0[3] = __builtin_amdgcn_mfma_scale_f32_16x16x128_f8f6f4(A0, b3, acc0[3], 0, 0, 0, SCL1, 0, SCL1);
        acc1[3] = __builtin_amdgcn_mfma_scale_f32_16x16x128_f8f6f4(A1, b3, acc1[3], 0, 0, 0, SCL1, 0, SCL1);

        i32x8 b4 = *(const i32x8*)(Wb + 8192);
        i32x8 b5 = *(const i32x8*)(Wb + 10240);
        i32x8 b6 = *(const i32x8*)(Wb + 12288);
        i32x8 b7 = *(const i32x8*)(Wb + 14336);

        acc0[4] = __builtin_amdgcn_mfma_scale_f32_16x16x128_f8f6f4(A0, b4, acc0[4], 0, 0, 0, SCL1, 0, SCL1);
        acc1[4] = __builtin_amdgcn_mfma_scale_f32_16x16x128_f8f6f4(A1, b4, acc1[4], 0, 0, 0, SCL1, 0, SCL1);
        acc0[5] = __builtin_amdgcn_mfma_scale_f32_16x16x128_f8f6f4(A0, b5, acc0[5], 0, 0, 0, SCL1, 0, SCL1);
        acc1[5] = __builtin_amdgcn_mfma_scale_f32_16x16x128_f8f6f4(A1, b5, acc1[5], 0, 0, 0, SCL1, 0, SCL1);
        acc0[6] = __builtin_amdgcn_mfma_scale_f32_16x16x128_f8f6f4(A0, b6, acc0[6], 0, 0, 0, SCL1, 0, SCL1);
        acc1[6] = __builtin_amdgcn_mfma_scale_f32_16x16x128_f8f6f4(A1, b6, acc1[6], 0, 0, 0, SCL1, 0, SCL1);
        acc0[7] = __builtin_amdgcn_mfma_scale_f32_16x16x128_f8f6f4(A0, b7, acc0[7], 0, 0, 0, SCL1, 0, SCL1);
        acc1[7] = __builtin_amdgcn_mfma_scale_f32_16x16x128_f8f6f4(A1, b7, acc1[7], 0, 0, 0, SCL1, 0, SCL1);

        Wb += 16384;
        rem += 8;
        if (rem >= 26) { rem -= 26; a += 1; }
    }

    if (q == 5) {
        // tail d=84: qd0 slots 672/673, qd1 674/675 (RBF); qd2 676(pos)/677(0);
        // qd3 678/679 (0). State (a,rem) points at d=84; clamp a for safe reads.
        i32x8 b0 = *(const i32x8*)(Wb);
        i32x8 b1 = *(const i32x8*)(Wb + 2048);
        i32x8 b2 = *(const i32x8*)(Wb + 4096);
        i32x8 b3 = *(const i32x8*)(Wb + 6144);

        int rem1 = rem + 1, a1 = a;
        if (rem1 == 26) { rem1 = 0; a1 = a + 1; }
        int ac  = a  > 25 ? 25 : a;
        int a1c = a1 > 25 ? 25 : a1;

        uint2 jR0a = jT[rem*65  + rl0], jR0b = jT[rem1*65 + rl0];
        uint2 jR1a = jT[rem*65  + rl1], jR1b = jT[rem1*65 + rl1];
        float4 xiR0a = iT[il0 + ac], xiR0b = iT[il0 + a1c];
        float4 xiR1a = iT[il1 + ac], xiR1b = iT[il1 + a1c];

        uint4 p0a = gen16(xiR0a, bflo(jR0a.x), bfhi(jR0a.x), bflo(jR0a.y), CC);
        uint4 p0b = gen16(xiR0b, bflo(jR0b.x), bfhi(jR0b.x), bflo(jR0b.y), CC);
        uint4 p1a = gen16(xiR1a, bflo(jR1a.x), bfhi(jR1a.x), bflo(jR1a.y), CC);
        uint4 p1b = gen16(xiR1b, bflo(jR1b.x), bfhi(jR1b.x), bflo(jR1b.y), CC);

        if (qd == 2) {   // slot 676 = positional; 677 = zero
            int dc0, dc1;
            {
                int j0 = JrowS[rl0], j1 = JrowS[rl1];
                int off  = Ridx[i0] - Ridx[j0];
                int same = (chain[i0] == chain[j0]);
                int dc = off + 32; dc = dc < 0 ? 0 : (dc > 64 ? 64 : dc);
                dc0 = same ? dc : 65;
                off  = Ridx[i1] - Ridx[j1];
                same = (chain[i1] == chain[j1]);
                dc = off + 32; dc = dc < 0 ? 0 : (dc > 64 ? 64 : dc);
                dc1 = same ? dc : 65;
            }
            float e0[16], e1[16];
            #pragma unroll
            for (int f = 0; f < 16; f++) {
                float bv = bp[f];
                e0[f] = Wp[f*66 + dc0] + bv;
                e1[f] = Wp[f*66 + dc1] + bv;
            }
            int u0 = __builtin_amdgcn_cvt_pk_fp8_f32(e0[0], e0[1], 0, false);
            u0     = __builtin_amdgcn_cvt_pk_fp8_f32(e0[2], e0[3], u0, true);
            int u1 = __builtin_amdgcn_cvt_pk_fp8_f32(e0[4], e0[5], 0, false);
            u1     = __builtin_amdgcn_cvt_pk_fp8_f32(e0[6], e0[7], u1, true);
            int u2 = __builtin_amdgcn_cvt_pk_fp8_f32(e0[8], e0[9], 0, false);
            u2     = __builtin_amdgcn_cvt_pk_fp8_f32(e0[10], e0[11], u2, true);
            int u3 = __builtin_amdgcn_cvt_pk_fp8_f32(e0[12], e0[13], 0, false);
            u3     = __builtin_amdgcn_cvt_pk_fp8_f32(e0[14], e0[15], u3, true);
            p0a = make_uint4((unsigned)u0,(unsigned)u1,(unsigned)u2,(unsigned)u3);
            u0 = __builtin_amdgcn_cvt_pk_fp8_f32(e1[0], e1[1], 0, false);
            u0 = __builtin_amdgcn_cvt_pk_fp8_f32(e1[2], e1[3], u0, true);
            u1 = __builtin_amdgcn_cvt_pk_fp8_f32(e1[4], e1[5], 0, false);
            u1 = __builtin_amdgcn_cvt_pk_fp8_f32(e1[6], e1[7], u1, true);
            u2 = __builtin_amdgcn_cvt_pk_fp8_f32(e1[8], e1[9], 0, false);
            u2 = __builtin_amdgcn_cvt_pk_fp8_f32(e1[10], e1[11], u2, true);
            u3 = __builtin_amdgcn_cvt_pk_fp8_f32(e1[12], e1[13], 0, false);
            u3 = __builtin_amdgcn_cvt_pk_fp8_f32(e1[14], e1[15], u3, true);
            p1a = make_uint4((unsigned)u0,(unsigned)u1,(unsigned)u2,(unsigned)u3);
            p0b = make_uint4(0,0,0,0);
            p1b = make_uint4(0,0,0,0);
        }
        if (qd == 3) {
            p0a = make_uint4(0,0,0,0); p0b = make_uint4(0,0,0,0);
            p1a = make_uint4(0,0,0,0); p1b = make_uint4(0,0,0,0);
        }

        i32x8 A0, A1;
        A0[0]=p0a.x; A0[1]=p0a.y; A0[2]=p0a.z; A0[3]=p0a.w;
        A0[4]=p0b.x; A0[5]=p0b.y; A0[6]=p0b.z; A0[7]=p0b.w;
        A1[0]=p1a.x; A1[1]=p1a.y; A1[2]=p1a.z; A1[3]=p1a.w;
        A1[4]=p1b.x; A1[5]=p1b.y; A1[6]=p1b.z; A1[7]=p1b.w;

        acc0[0] = __builtin_amdgcn_mfma_scale_f32_16x16x128_f8f6f4(A0, b0, acc0[0], 0, 0, 0, SCL1, 0, SCL1);
        acc1[0] = __builtin_amdgcn_mfma_scale_f32_16x16x128_f8f6f4(A1, b0, acc1[0], 0, 0, 0, SCL1, 0, SCL1);
        acc0[1] = __builtin_amdgcn_mfma_scale_f32_16x16x128_f8f6f4(A0, b1, acc0[1], 0, 0, 0, SCL1, 0, SCL1);
        acc1[1] = __builtin_amdgcn_mfma_scale_f32_16x16x128_f8f6f4(A1, b1, acc1[1], 0, 0, 0, SCL1, 0, SCL1);
        acc0[2] = __builtin_amdgcn_mfma_scale_f32_16x16x128_f8f6f4(A0, b2, acc0[2], 0, 0, 0, SCL1, 0, SCL1);
        acc1[2] = __builtin_amdgcn_mfma_scale_f32_16x16x128_f8f6f4(A1, b2, acc1[2], 0, 0, 0, SCL1, 0, SCL1);
        acc0[3] = __builtin_amdgcn_mfma_scale_f32_16x16x128_f8f6f4(A0, b3, acc0[3], 0, 0, 0, SCL1, 0, SCL1);
        acc1[3] = __builtin_amdgcn_mfma_scale_f32_16x16x128_f8f6f4(A1, b3, acc1[3], 0, 0, 0, SCL1, 0, SCL1);

        i32x8 b4 = *(const i32x8*)(Wb + 8192);
        i32x8 b5 = *(const i32x8*)(Wb + 10240);
        i32x8 b6 = *(const i32x8*)(Wb + 12288);
        i32x8 b7 = *(const i32x8*)(Wb + 14336);

        acc0[4] = __builtin_amdgcn_mfma_scale_f32_16x16x128_f8f6f4(A0, b4, acc0[4], 0, 0, 0, SCL1, 0, SCL1);
        acc1[4] = __builtin_amdgcn_mfma_scale_f32_16x16x128_f8f6f4(A1, b4, acc1[4], 0, 0, 0, SCL1, 0, SCL1);
        acc0[5] = __builtin_amdgcn_mfma_scale_f32_16x16x128_f8f6f4(A0, b5, acc0[5], 0, 0, 0, SCL1, 0, SCL1);
        acc1[5] = __builtin_amdgcn_mfma_scale_f32_16x16x128_f8f6f4(A1, b5, acc1[5], 0, 0, 0, SCL1, 0, SCL1);
        acc0[6] = __builtin_amdgcn_mfma_scale_f32_16x16x128_f8f6f4(A0, b6, acc0[6], 0, 0, 0, SCL1, 0, SCL1);
        acc1[6] = __builtin_amdgcn_mfma_scale_f32_16x16x128_f8f6f4(A1, b6, acc1[6], 0, 0, 0, SCL1, 0, SCL1);
        acc0[7] = __builtin_amdgcn_mfma_scale_f32_16x16x128_f8f6f4(A0, b7, acc0[7], 0, 0, 0, SCL1, 0, SCL1);
        acc1[7] = __builtin_amdgcn_mfma_scale_f32_16x16x128_f8f6f4(A1, b7, acc1[7], 0, 0, 0, SCL1, 0, SCL1);
    }

    // epilogue: bf16 partials. D layout: col = lane&15, row = qd*4 + rr.
    #pragma unroll
    for (int nt = 0; nt < 8; nt++) {
        int col = nt*16 + mlane;
        #pragma unroll
        for (int rr = 0; rr < 4; rr++) {
            int g0 = bx*64 + w*32 + qd*4 + rr;
            Ep[(size_t)g0*NOUT + col]      = f2bf(acc0[nt][rr]);
            Ep[(size_t)(g0+16)*NOUT + col] = f2bf(acc1[nt][rr]);
        }
    }
}

// ---------------------------------------------------------------- kernel D --
// Wave per row: 64 lanes x 2 cols (uint bf16-pair loads), shuffle-only LN.
__global__ __launch_bounds__(256) void kD(const float* __restrict__ ge,
                                          const float* __restrict__ be,
                                          char* __restrict__ ws,
                                          float* __restrict__ out)
{
    const unsigned* Ep = (const unsigned*)(ws + OFF_EPART);
    const int t = threadIdx.x, wv = t >> 6, lane = t & 63;
    const int row = blockIdx.x*4 + wv;
    const size_t qs = (size_t)MTOT * 64;           // uints per partial set
    size_t b = (size_t)row*64 + lane;

    float v0 = 0.f, v1 = 0.f;
    #pragma unroll
    for (int qq = 0; qq < KSPLIT; qq++) {
        unsigned u = Ep[b + (size_t)qq*qs];
        v0 += bf2f((unsigned short)(u & 0xffffu));
        v1 += bf2f((unsigned short)(u >> 16));
    }

    float S = v0 + v1, Q = v0*v0 + v1*v1;
    #pragma unroll
    for (int off = 32; off; off >>= 1) {
        S += __shfl_xor(S, off, 64);
        Q += __shfl_xor(Q, off, 64);
    }
    float mean = S * (1.0f/128.0f);
    float var  = Q * (1.0f/128.0f) - mean*mean;
    float rstd = rsqrtf(var + 1e-5f);
    float2 o;
    o.x = (v0 - mean) * rstd * ge[2*lane]   + be[2*lane];
    o.y = (v1 - mean) * rstd * ge[2*lane+1] + be[2*lane+1];
    ((float2*)(out + OUT_E))[(size_t)row*64 + lane] = o;
}

// ------------------------------------------------------------------- launch --
extern "C" void kernel_launch(void* const* d_in, const int* in_sizes, int n_in,
                              void* d_out, int out_size, void* d_ws, size_t ws_size,
                              hipStream_t stream)
{
    const float* X     = (const float*)d_in[0];
    const int*   Ridx  = (const int*)d_in[2];
    const int*   chain = (const int*)d_in[3];
    const float* Xm    = (const float*)d_in[4];
    const float* prot  = (const float*)d_in[5];
    const float* dna   = (const float*)d_in[6];
    const float* rna   = (const float*)d_in[7];
    const int*   ptype = (const int*)d_in[8];
    const float* Wp    = (const float*)d_in[9];
    const float* bp    = (const float*)d_in[10];
    const float* We    = (const float*)d_in[11];
    const float* Wn    = (const float*)d_in[12];
    const float* ge    = (const float*)d_in[13];
    const float* be    = (const float*)d_in[14];
    const float* gn    = (const float*)d_in[15];
    const float* bn    = (const float*)d_in[16];
    char* ws = (char*)d_ws;
    float* out = (float*)d_out;

    kPrep<<<dim3(NRES + 384), dim3(256), 0, stream>>>(X, Xm, prot, dna, rna,
            ptype, Wn, gn, bn, We, ws, out);
    kC<<<dim3(240, KSPLIT), dim3(128), 0, stream>>>(Ridx, chain, Wp, bp, ws);
    kD<<<dim3(MTOT/4), dim3(256), 0, stream>>>(ge, be, ws, out);
}